// Round 14
// baseline (321.733 us; speedup 1.0000x reference)
//
#include <hip/hip_runtime.h>
#include <hip/hip_bf16.h>
#include <hip/hip_fp16.h>
#include <math.h>

#define N_NODES 100000
#define N_EDGES 1600000
#define NBUK 196          // buckets = dst>>9 ; 99999>>9 = 195
#define NSB  256          // scatter blocks == grid of csr_build
#define EPB  6250         // edges per block (256*6250 = 1.6M exact)
// IN=128, HD=128, H=4, D=32

typedef __attribute__((ext_vector_type(8))) short bf16x8;
typedef __attribute__((ext_vector_type(4))) float f32x4;
typedef __attribute__((ext_vector_type(2))) float f32x2;

__device__ __forceinline__ short f2bf_s(float x) {
    __hip_bfloat16 b = __float2bfloat16(x);
    return *reinterpret_cast<short*>(&b);
}
__device__ __forceinline__ __half2 bc2(unsigned u) {
    return *reinterpret_cast<__half2*>(&u);
}
__device__ __forceinline__ unsigned bcu(__half2 h) {
    return *reinterpret_cast<unsigned*>(&h);
}
__device__ __forceinline__ unsigned pack2h(float a, float b) {
    __half ha = __float2half(a), hb = __float2half(b);
    return (unsigned)*reinterpret_cast<unsigned short*>(&ha)
         | ((unsigned)*reinterpret_cast<unsigned short*>(&hb) << 16);
}

// device-scope grid barrier: monotonic arrival counter (no reset, no ABA)
__device__ __forceinline__ void gbar(int* cnt, int target) {
    __syncthreads();
    if (threadIdx.x == 0) {
        __hip_atomic_fetch_add(cnt, 1, __ATOMIC_ACQ_REL, __HIP_MEMORY_SCOPE_AGENT);
        while (__hip_atomic_load(cnt, __ATOMIC_ACQUIRE, __HIP_MEMORY_SCOPE_AGENT) < target)
            __builtin_amdgcn_s_sleep(2);
    }
    __syncthreads();
}

// ============================================================
// csr_build: ONE persistent kernel (grid = 256 blocks, all-resident)
//   P1: per-block bucket histogram (per-wave LDS) + Wtb transpose
//   P2: blocks 0..195 scan histT row (per-bucket exclusive over blocks)
//   P3: block 0 scans bucket sums -> bscan
//   P4: scatter edges -> bucket-contiguous tmp (LDS rank atomics)
//   P5: blocks 0..195 counting-sort bucket by dst low 9 bits; emit
//       sorted_src (src*128 byte offsets) + CSR offs
// ============================================================
__global__ __launch_bounds__(256) void csr_build(
    const int* __restrict__ src, const int* __restrict__ dst,
    const float* __restrict__ Wq, const float* __restrict__ Wk,
    const float* __restrict__ Wv, const float* __restrict__ Ws,
    unsigned short* __restrict__ Wtb,
    int* __restrict__ histT, int* __restrict__ boffs,
    int* __restrict__ bsums, int* __restrict__ bscan,
    unsigned* __restrict__ tmp, int* __restrict__ sorted_src,
    int* __restrict__ offs, int* __restrict__ barcnt)
{
    __shared__ int shm[1280];
    const int bid = blockIdx.x, tid = threadIdx.x;

    // ---- P1: histogram + W transpose
    for (int t = tid; t < 4 * NBUK; t += 256) shm[t] = 0;
    __syncthreads();
    {
        int w = tid >> 6;
        for (int i = tid; i < EPB; i += 256)
            atomicAdd(&shm[w * NBUK + (dst[bid * EPB + i] >> 9)], 1);
        int j = bid * 256 + tid;   // 65536 total
        int m = j >> 14;
        int rem = j & 16383;
        int c = rem >> 7;
        int kk = rem & 127;
        const float* W = (m == 0) ? Wq : (m == 1) ? Wk : (m == 2) ? Wv : Ws;
        Wtb[j] = (unsigned short)f2bf_s(W[(size_t)kk * 128 + c]);
    }
    __syncthreads();
    if (tid < NBUK)
        histT[tid * NSB + bid] = shm[tid] + shm[NBUK + tid]
                               + shm[2 * NBUK + tid] + shm[3 * NBUK + tid];
    gbar(barcnt, 1 * NSB);

    // ---- P2: per-bucket exclusive scan over blocks (blocks 0..195)
    if (bid < NBUK) {
        int x = histT[bid * NSB + tid];
        shm[tid] = x;
        __syncthreads();
        #pragma unroll
        for (int o = 1; o < 256; o <<= 1) {
            int t = (tid >= o) ? shm[tid - o] : 0;
            __syncthreads();
            shm[tid] += t;
            __syncthreads();
        }
        boffs[bid * NSB + tid] = shm[tid] - x;
        if (tid == 255) bsums[bid] = shm[255];
    }
    gbar(barcnt, 2 * NSB);

    // ---- P3: bucket bases (block 0)
    if (bid == 0) {
        int x = (tid < NBUK) ? bsums[tid] : 0;
        shm[tid] = x;
        __syncthreads();
        #pragma unroll
        for (int o = 1; o < 256; o <<= 1) {
            int t = (tid >= o) ? shm[tid - o] : 0;
            __syncthreads();
            shm[tid] += t;
            __syncthreads();
        }
        if (tid < NBUK) bscan[tid] = shm[tid] - x;
    }
    gbar(barcnt, 3 * NSB);

    // ---- P4: scatter to bucket-contiguous tmp
    {
        if (tid < NBUK) shm[tid] = 0;
        __syncthreads();
        for (int i = tid; i < EPB; i += 256) {
            int e = bid * EPB + i;
            int d = dst[e];
            int s = src[e];
            int j = d >> 9;
            int r = atomicAdd(&shm[j], 1);
            int pos = boffs[j * NSB + bid] + bscan[j] + r;
            tmp[pos] = ((unsigned)(d & 511) << 17) | (unsigned)s;
        }
    }
    gbar(barcnt, 4 * NSB);

    // ---- P5: counting sort within bucket (blocks 0..195)
    if (bid < NBUK) {
        int* h  = shm;          // 512
        int* o_ = shm + 512;    // 512
        int* s_ = shm + 1024;   // 256
        int base = bscan[bid];
        int next = (bid == NBUK - 1) ? N_EDGES : bscan[bid + 1];
        int cnt = next - base;

        h[tid] = 0; h[tid + 256] = 0;
        __syncthreads();
        for (int i = tid; i < cnt; i += 256)
            atomicAdd(&h[tmp[base + i] >> 17], 1);
        __syncthreads();

        int a0 = h[2 * tid], a1 = h[2 * tid + 1];
        s_[tid] = a0 + a1;
        __syncthreads();
        #pragma unroll
        for (int o = 1; o < 256; o <<= 1) {
            int t = (tid >= o) ? s_[tid - o] : 0;
            __syncthreads();
            s_[tid] += t;
            __syncthreads();
        }
        int eb = s_[tid] - a0 - a1;
        o_[2 * tid] = eb;
        o_[2 * tid + 1] = eb + a0;
        __syncthreads();

        for (int t = tid; t < 512; t += 256) {
            int n = bid * 512 + t;
            if (n < N_NODES) offs[n] = base + o_[t];
        }
        __syncthreads();

        for (int i = tid; i < cnt; i += 256) {
            unsigned rec = tmp[base + i];
            int r = atomicAdd(&o_[rec >> 17], 1);
            sorted_src[base + r] = (int)((rec & 0x1FFFFu) << 7);  // src*128
        }
    }
}

// ============================================================
// MFMA GEMM v2: LDS-staged A, LDS-staged epilogue, coalesced I/O
//   block = 32 rows; 4 waves, wave = matrix (0=q,1=k,2=v,3=skip)
//   Outputs: q8[n] 128B fp8 | vh[n] 128 half | ks_[n] k||skip 256 half
// ============================================================
__global__ __launch_bounds__(256) void gemm_mfma(
    const float* __restrict__ feat, const unsigned short* __restrict__ Wtb,
    const float* __restrict__ bq, const float* __restrict__ bk,
    const float* __restrict__ bv, const float* __restrict__ bs,
    unsigned char* __restrict__ q8, __half* __restrict__ vh,
    __half* __restrict__ ks_)
{
    __shared__ __align__(16) unsigned short Atile[32][136];   // 272 B rows
    __shared__ __align__(16) unsigned char  Oq8[32][144];     // 128 used
    __shared__ __align__(16) unsigned char  Ovh[32][272];     // 256 used
    __shared__ __align__(16) unsigned char  Oks[32][528];     // 512 used

    const int tid = threadIdx.x;
    const int r0  = blockIdx.x * 32;     // 3125 * 32 = 100000 exact

    {
        int row = tid >> 3;
        int cg  = (tid & 7) * 16;
        const float4* fp = (const float4*)(feat + (size_t)(r0 + row) * 128 + cg);
        float4 f0 = fp[0], f1 = fp[1], f2 = fp[2], f3 = fp[3];
        unsigned short* ap = &Atile[row][cg];
        ap[0]  = (unsigned short)f2bf_s(f0.x); ap[1]  = (unsigned short)f2bf_s(f0.y);
        ap[2]  = (unsigned short)f2bf_s(f0.z); ap[3]  = (unsigned short)f2bf_s(f0.w);
        ap[4]  = (unsigned short)f2bf_s(f1.x); ap[5]  = (unsigned short)f2bf_s(f1.y);
        ap[6]  = (unsigned short)f2bf_s(f1.z); ap[7]  = (unsigned short)f2bf_s(f1.w);
        ap[8]  = (unsigned short)f2bf_s(f2.x); ap[9]  = (unsigned short)f2bf_s(f2.y);
        ap[10] = (unsigned short)f2bf_s(f2.z); ap[11] = (unsigned short)f2bf_s(f2.w);
        ap[12] = (unsigned short)f2bf_s(f3.x); ap[13] = (unsigned short)f2bf_s(f3.y);
        ap[14] = (unsigned short)f2bf_s(f3.z); ap[15] = (unsigned short)f2bf_s(f3.w);
    }
    __syncthreads();

    const int mat = tid >> 6;
    const int l   = tid & 63;
    const int lr  = l & 15;
    const int lg  = l >> 4;
    const float* bias = (mat == 0) ? bq : (mat == 1) ? bk : (mat == 2) ? bv : bs;

    f32x4 acc[2][8];
    #pragma unroll
    for (int i = 0; i < 2; i++)
        #pragma unroll
        for (int j = 0; j < 8; j++) acc[i][j] = (f32x4){0.f, 0.f, 0.f, 0.f};

    #pragma unroll
    for (int kks = 0; kks < 4; kks++) {
        const int k0 = kks * 32 + lg * 8;
        bf16x8 a[2], b[8];
        #pragma unroll
        for (int rf = 0; rf < 2; rf++)
            a[rf] = *(const bf16x8*)&Atile[rf * 16 + lr][k0];
        #pragma unroll
        for (int cf = 0; cf < 8; cf++) {
            int col = cf * 16 + lr;
            b[cf] = *(const bf16x8*)(Wtb + ((size_t)mat * 128 + col) * 128 + k0);
        }
        #pragma unroll
        for (int rf = 0; rf < 2; rf++)
            #pragma unroll
            for (int cf = 0; cf < 8; cf++)
                acc[rf][cf] = __builtin_amdgcn_mfma_f32_16x16x32_bf16(
                    b[cf], a[rf], acc[rf][cf], 0, 0, 0);
    }

    #pragma unroll
    for (int rf = 0; rf < 2; rf++) {
        int rl = rf * 16 + lr;
        #pragma unroll
        for (int cf = 0; cf < 8; cf++) {
            int colb = cf * 16 + lg * 4;
            float4 b4 = *(const float4*)(bias + colb);
            float a0 = acc[rf][cf][0] + b4.x, a1 = acc[rf][cf][1] + b4.y;
            float a2 = acc[rf][cf][2] + b4.z, a3 = acc[rf][cf][3] + b4.w;
            if (mat == 0) {
                unsigned u = (unsigned)__builtin_amdgcn_cvt_pk_fp8_f32(a0, a1, 0, false);
                u = (unsigned)__builtin_amdgcn_cvt_pk_fp8_f32(a2, a3, (int)u, true);
                *(unsigned*)&Oq8[rl][colb] = u;
            } else if (mat == 2) {
                uint2 pk; pk.x = pack2h(a0, a1); pk.y = pack2h(a2, a3);
                *(uint2*)&Ovh[rl][colb * 2] = pk;
            } else {
                uint2 pk; pk.x = pack2h(a0, a1); pk.y = pack2h(a2, a3);
                *(uint2*)&Oks[rl][((mat == 3) ? 256 : 0) + colb * 2] = pk;
            }
        }
    }
    __syncthreads();

    {
        int row = tid >> 3;
        int c16 = (tid & 7) * 16;
        *(uint4*)(q8 + (size_t)(r0 + row) * 128 + c16) = *(const uint4*)&Oq8[row][c16];
        {
            char* gp = (char*)vh + (size_t)(r0 + row) * 256 + (tid & 7) * 32;
            const char* lp = (const char*)&Ovh[row][0] + (tid & 7) * 32;
            ((uint4*)gp)[0] = ((const uint4*)lp)[0];
            ((uint4*)gp)[1] = ((const uint4*)lp)[1];
        }
        {
            char* gp = (char*)ks_ + (size_t)(r0 + row) * 512 + (tid & 7) * 64;
            const char* lp = (const char*)&Oks[row][0] + (tid & 7) * 64;
            ((uint4*)gp)[0] = ((const uint4*)lp)[0];
            ((uint4*)gp)[1] = ((const uint4*)lp)[1];
            ((uint4*)gp)[2] = ((const uint4*)lp)[2];
            ((uint4*)gp)[3] = ((const uint4*)lp)[3];
        }
    }
}

// ============================================================
// fused dst-centric aggregation + gate + LN + PReLU
//   one wave per node; quarter-wave per edge; per edge: uint2 fp8 q gather
//   + uint4 fp16 v gather (384B/edge); depth-3 pipeline, decoupled idx loads
// ============================================================
__global__ __launch_bounds__(256) void node_fused(
    const unsigned char* __restrict__ q8, const __half* __restrict__ vh,
    const __half* __restrict__ ks_,
    const int* __restrict__ offs, const int* __restrict__ sorted_src,
    const float* __restrict__ wg, const float* __restrict__ bg,
    const float* __restrict__ gamma, const float* __restrict__ beta,
    const float* __restrict__ pa, float* __restrict__ out)
{
    int wid = threadIdx.x >> 6;
    int l   = threadIdx.x & 63;
    int qtr = l >> 4;
    int c   = l & 15;
    int n = blockIdx.x * 4 + wid;
    if (n >= N_NODES) return;

    int start = offs[n];
    int end   = (n + 1 < N_NODES) ? offs[n + 1] : N_EDGES;

    const uint4* krow = (const uint4*)ks_;
    uint4 kp  = krow[(size_t)n * 32 + c];
    uint4 sp4 = krow[(size_t)n * 32 + 16 + c];

    float kf[8];
    {
        __half2 h;
        h = bc2(kp.x); kf[0] = __low2float(h); kf[1] = __high2float(h);
        h = bc2(kp.y); kf[2] = __low2float(h); kf[3] = __high2float(h);
        h = bc2(kp.z); kf[4] = __low2float(h); kf[5] = __high2float(h);
        h = bc2(kp.w); kf[6] = __low2float(h); kf[7] = __high2float(h);
    }

    float den = 0.f;
    __half2 ag0 = bc2(0u), ag1 = bc2(0u), ag2 = bc2(0u), ag3 = bc2(0u);
    const float C = 0.25503483f;   // (1/sqrt(32)) * log2(e)

    const char* qb = (const char*)q8 + c * 8;     // + src*128
    const char* vb = (const char*)vh + c * 16;    // + src*256

    int base = start;
    int sA = sorted_src[min(base + qtr, end - 1)];
    uint2 qA = *(const uint2*)(qb + sA);
    uint4 vA = *(const uint4*)(vb + 2 * (size_t)sA);
    bool hasB = (base + 4) < end;
    uint2 qB; uint4 vB;
    if (hasB) {
        int sB = sorted_src[min(base + 4 + qtr, end - 1)];
        qB = *(const uint2*)(qb + sB);
        vB = *(const uint4*)(vb + 2 * (size_t)sB);
    }
    int sC = ((base + 8) < end) ? sorted_src[min(base + 8 + qtr, end - 1)] : 0;

    for (;;) {
        bool hasC = (base + 8) < end;
        uint2 qC; uint4 vC;
        if (hasC) {
            qC = *(const uint2*)(qb + sC);
            vC = *(const uint4*)(vb + 2 * (size_t)sC);
        }
        int sD = ((base + 12) < end) ? sorted_src[min(base + 12 + qtr, end - 1)] : 0;

        f32x2 q01 = __builtin_amdgcn_cvt_pk_f32_fp8((int)qA.x, false);
        f32x2 q23 = __builtin_amdgcn_cvt_pk_f32_fp8((int)qA.x, true);
        f32x2 q45 = __builtin_amdgcn_cvt_pk_f32_fp8((int)qA.y, false);
        f32x2 q67 = __builtin_amdgcn_cvt_pk_f32_fp8((int)qA.y, true);
        float d = q01.x * kf[0] + q01.y * kf[1] + q23.x * kf[2] + q23.y * kf[3]
                + q45.x * kf[4] + q45.y * kf[5] + q67.x * kf[6] + q67.y * kf[7];
        d += __shfl_xor(d, 1);
        d += __shfl_xor(d, 2);
        float e = (base + qtr < end) ? __builtin_amdgcn_exp2f(d * C) : 0.f;
        den += e;
        __half2 e2 = __float2half2_rn(e);
        ag0 = __hfma2(e2, bc2(vA.x), ag0);
        ag1 = __hfma2(e2, bc2(vA.y), ag1);
        ag2 = __hfma2(e2, bc2(vA.z), ag2);
        ag3 = __hfma2(e2, bc2(vA.w), ag3);

        if (!hasB) break;
        base += 4;
        qA = qB; vA = vB; qB = qC; vB = vC; sC = sD; hasB = hasC;
    }

    den += __shfl_xor(den, 16);
    den += __shfl_xor(den, 32);
    ag0 = __hadd2(ag0, bc2(__shfl_xor(bcu(ag0), 16)));
    ag1 = __hadd2(ag1, bc2(__shfl_xor(bcu(ag1), 16)));
    ag2 = __hadd2(ag2, bc2(__shfl_xor(bcu(ag2), 16)));
    ag3 = __hadd2(ag3, bc2(__shfl_xor(bcu(ag3), 16)));
    ag0 = __hadd2(ag0, bc2(__shfl_xor(bcu(ag0), 32)));
    ag1 = __hadd2(ag1, bc2(__shfl_xor(bcu(ag1), 32)));
    ag2 = __hadd2(ag2, bc2(__shfl_xor(bcu(ag2), 32)));
    ag3 = __hadd2(ag3, bc2(__shfl_xor(bcu(ag3), 32)));

    float rd = 1.f / den;
    float r[8];
    r[0] = __low2float(ag0) * rd; r[1] = __high2float(ag0) * rd;
    r[2] = __low2float(ag1) * rd; r[3] = __high2float(ag1) * rd;
    r[4] = __low2float(ag2) * rd; r[5] = __high2float(ag2) * rd;
    r[6] = __low2float(ag3) * rd; r[7] = __high2float(ag3) * rd;

    float s[8];
    s[0] = __low2float(bc2(sp4.x)); s[1] = __high2float(bc2(sp4.x));
    s[2] = __low2float(bc2(sp4.y)); s[3] = __high2float(bc2(sp4.y));
    s[4] = __low2float(bc2(sp4.z)); s[5] = __high2float(bc2(sp4.z));
    s[6] = __low2float(bc2(sp4.w)); s[7] = __high2float(bc2(sp4.w));

    const float4* wgf = (const float4*)wg;
    float4 w0a = wgf[2 * c],      w0b = wgf[2 * c + 1];
    float4 w1a = wgf[32 + 2 * c], w1b = wgf[32 + 2 * c + 1];
    float4 w2a = wgf[64 + 2 * c], w2b = wgf[64 + 2 * c + 1];
    float w0[8] = {w0a.x, w0a.y, w0a.z, w0a.w, w0b.x, w0b.y, w0b.z, w0b.w};
    float w1[8] = {w1a.x, w1a.y, w1a.z, w1a.w, w1b.x, w1b.y, w1b.z, w1b.w};
    float w2[8] = {w2a.x, w2a.y, w2a.z, w2a.w, w2b.x, w2b.y, w2b.z, w2b.w};

    float gs = 0.f;
    #pragma unroll
    for (int j = 0; j < 8; j++)
        gs += s[j] * w0[j] + r[j] * w1[j] + (s[j] - r[j]) * w2[j];
    gs += __shfl_xor(gs, 1);
    gs += __shfl_xor(gs, 2);
    gs += __shfl_xor(gs, 4);
    gs += __shfl_xor(gs, 8);
    float g = 1.f / (1.f + __builtin_amdgcn_exp2f(-(gs + bg[0]) * 1.4426950408889634f));

    #pragma unroll
    for (int j = 0; j < 8; j++) r[j] = g * s[j] + (1.f - g) * r[j];

    float mu = 0.f;
    #pragma unroll
    for (int j = 0; j < 8; j++) mu += r[j];
    mu += __shfl_xor(mu, 1);
    mu += __shfl_xor(mu, 2);
    mu += __shfl_xor(mu, 4);
    mu += __shfl_xor(mu, 8);
    mu *= (1.f / 128.f);

    float var = 0.f;
    #pragma unroll
    for (int j = 0; j < 8; j++) { float e0 = r[j] - mu; var += e0 * e0; }
    var += __shfl_xor(var, 1);
    var += __shfl_xor(var, 2);
    var += __shfl_xor(var, 4);
    var += __shfl_xor(var, 8);
    var *= (1.f / 128.f);
    float inv = rsqrtf(var + 1e-5f);

    if (qtr == 0) {
        float4 ga = ((const float4*)gamma)[2 * c], gb = ((const float4*)gamma)[2 * c + 1];
        float4 ba = ((const float4*)beta)[2 * c],  bb = ((const float4*)beta)[2 * c + 1];
        float gm[8] = {ga.x, ga.y, ga.z, ga.w, gb.x, gb.y, gb.z, gb.w};
        float bt[8] = {ba.x, ba.y, ba.z, ba.w, bb.x, bb.y, bb.z, bb.w};
        float al = pa[0];
        float y[8];
        #pragma unroll
        for (int j = 0; j < 8; j++) {
            float t = (r[j] - mu) * inv * gm[j] + bt[j];
            y[j] = (t > 0.f) ? t : al * t;
        }
        float4* op = (float4*)(out + (size_t)n * 128 + c * 8);
        op[0] = (float4){y[0], y[1], y[2], y[3]};
        op[1] = (float4){y[4], y[5], y[6], y[7]};
    }
}

// ============================================================
extern "C" void kernel_launch(void* const* d_in, const int* in_sizes, int n_in,
                              void* d_out, int out_size, void* d_ws, size_t ws_size,
                              hipStream_t stream) {
    const float* feat  = (const float*)d_in[0];
    const int*   src   = (const int*)d_in[1];
    const int*   dst   = (const int*)d_in[2];
    const float* Wq    = (const float*)d_in[3];
    const float* bq    = (const float*)d_in[4];
    const float* Wk    = (const float*)d_in[5];
    const float* bk    = (const float*)d_in[6];
    const float* Wv    = (const float*)d_in[7];
    const float* bv    = (const float*)d_in[8];
    const float* Wsk   = (const float*)d_in[9];
    const float* bsk   = (const float*)d_in[10];
    const float* Wg    = (const float*)d_in[11];
    const float* bg    = (const float*)d_in[12];
    const float* gamma = (const float*)d_in[13];
    const float* beta  = (const float*)d_in[14];
    const float* pa    = (const float*)d_in[15];
    float* out = (float*)d_out;

    char* p = (char*)d_ws;
    unsigned char* q8  = (unsigned char*)p;  p += (size_t)N_NODES * 128;       // 12.8 MB
    __half*        vh  = (__half*)p;         p += (size_t)N_NODES * 128 * 2;   // 25.6 MB
    __half*        ks_ = (__half*)p;         p += (size_t)N_NODES * 256 * 2;   // 51.2 MB
    unsigned short* Wtb = (unsigned short*)p;  p += (size_t)4 * 128 * 128 * 2;
    int*      sorted_src = (int*)p;      p += (size_t)N_EDGES * 4;
    unsigned* tmp        = (unsigned*)p; p += (size_t)N_EDGES * 4;
    int*      histT      = (int*)p;      p += (size_t)NBUK * NSB * 4;
    int*      boffs      = (int*)p;      p += (size_t)NBUK * NSB * 4;
    int*      offs       = (int*)p;      p += (size_t)N_NODES * 4;
    int*      bsums      = (int*)p;      p += 4096;
    int*      bscan      = (int*)p;      p += 4096;
    int*      barcnt     = (int*)p;      p += 4096;

    hipMemsetAsync(barcnt, 0, 4, stream);
    csr_build<<<NSB, 256, 0, stream>>>(src, dst, Wq, Wk, Wv, Wsk, Wtb,
                                       histT, boffs, bsums, bscan,
                                       tmp, sorted_src, offs, barcnt);
    gemm_mfma<<<3125, 256, 0, stream>>>(feat, Wtb, bq, bk, bv, bsk, q8, vh, ks_);
    node_fused<<<(N_NODES + 3) / 4, 256, 0, stream>>>(q8, vh, ks_, offs, sorted_src,
                                                      Wg, bg, gamma, beta, pa, out);
}

// Round 15
// 241.042 us; speedup vs baseline: 1.3348x; 1.3348x over previous
//
#include <hip/hip_runtime.h>
#include <hip/hip_bf16.h>
#include <hip/hip_fp16.h>
#include <math.h>

#define N_NODES 100000
#define N_EDGES 1600000
#define NBUK 391          // buckets = dst>>8 ; 99999>>8 = 390
#define NSB2 1024         // hist/scatter blocks (4 per CU)
#define EPB2 1563         // edges per block (1024*1563 >= 1.6M, bounds-checked)
// IN=128, HD=128, H=4, D=32

typedef __attribute__((ext_vector_type(8))) short bf16x8;
typedef __attribute__((ext_vector_type(4))) float f32x4;
typedef __attribute__((ext_vector_type(2))) float f32x2;

__device__ __forceinline__ short f2bf_s(float x) {
    __hip_bfloat16 b = __float2bfloat16(x);
    return *reinterpret_cast<short*>(&b);
}
__device__ __forceinline__ __half2 bc2(unsigned u) {
    return *reinterpret_cast<__half2*>(&u);
}
__device__ __forceinline__ unsigned bcu(__half2 h) {
    return *reinterpret_cast<unsigned*>(&h);
}
__device__ __forceinline__ unsigned pack2h(float a, float b) {
    __half ha = __float2half(a), hb = __float2half(b);
    return (unsigned)*reinterpret_cast<unsigned short*>(&ha)
         | ((unsigned)*reinterpret_cast<unsigned short*>(&hb) << 16);
}

// ============================================================
// hist2_wt: blocks 0..1023 = per-block bucket histogram (per-wave LDS)
//           blocks 1024..1279 = W transpose -> bf16
//   histT layout: [bucket][block]
// ============================================================
__global__ __launch_bounds__(256) void hist2_wt(
    const int* __restrict__ dst,
    const float* __restrict__ Wq, const float* __restrict__ Wk,
    const float* __restrict__ Wv, const float* __restrict__ Ws,
    int* __restrict__ histT, unsigned short* __restrict__ Wtb)
{
    int bid = blockIdx.x, tid = threadIdx.x;
    if (bid < NSB2) {
        __shared__ int h[4 * NBUK];
        for (int t = tid; t < 4 * NBUK; t += 256) h[t] = 0;
        __syncthreads();
        int w = tid >> 6;
        for (int i = tid; i < EPB2; i += 256) {
            int e = bid * EPB2 + i;
            if (e < N_EDGES) atomicAdd(&h[w * NBUK + (dst[e] >> 8)], 1);
        }
        __syncthreads();
        for (int t = tid; t < NBUK; t += 256)
            histT[(size_t)t * NSB2 + bid] = h[t] + h[NBUK + t]
                                          + h[2 * NBUK + t] + h[3 * NBUK + t];
    } else {
        int j = (bid - NSB2) * 256 + tid;   // [0, 65536)
        int m = j >> 14;
        int rem = j & 16383;
        int c = rem >> 7;
        int kk = rem & 127;
        const float* W = (m == 0) ? Wq : (m == 1) ? Wk : (m == 2) ? Wv : Ws;
        Wtb[j] = (unsigned short)f2bf_s(W[(size_t)kk * 128 + c]);
    }
}

// ============================================================
// scan_block2: grid = NBUK; block b scans histT[b][0..1023] (4 chunks,
//   carry-chained) -> boffs (exclusive within bucket), bsums[b] = total
// ============================================================
__global__ __launch_bounds__(256) void scan_block2(
    const int* __restrict__ in, int* __restrict__ outlocal, int* __restrict__ bsums)
{
    __shared__ int s[256];
    int bid = blockIdx.x, tid = threadIdx.x;
    int carry = 0;
    #pragma unroll
    for (int ch = 0; ch < 4; ch++) {
        int i = ch * 256 + tid;
        int x = in[(size_t)bid * NSB2 + i];
        s[tid] = x;
        __syncthreads();
        #pragma unroll
        for (int o = 1; o < 256; o <<= 1) {
            int t = (tid >= o) ? s[tid - o] : 0;
            __syncthreads();
            s[tid] += t;
            __syncthreads();
        }
        outlocal[(size_t)bid * NSB2 + i] = carry + s[tid] - x;
        carry += s[255];
        __syncthreads();
    }
    if (tid == 0) bsums[bid] = carry;
}

// single block scans NBUK bucket sums (exclusive) -> bucket bases
__global__ __launch_bounds__(512) void scan_sums2(
    const int* __restrict__ bsums, int* __restrict__ bscan)
{
    __shared__ int s[512];
    int i = threadIdx.x;
    int x = (i < NBUK) ? bsums[i] : 0;
    s[i] = x;
    __syncthreads();
    #pragma unroll
    for (int o = 1; o < 512; o <<= 1) {
        int t = (i >= o) ? s[i - o] : 0;
        __syncthreads();
        s[i] += t;
        __syncthreads();
    }
    if (i < NBUK) bscan[i] = s[i] - x;
}

// ============================================================
// scatter2: edges -> bucket-contiguous tmp, LDS rank atomics only
//   rec = (dst&255)<<17 | src   (src < 2^17)
// ============================================================
__global__ __launch_bounds__(256) void scatter2(
    const int* __restrict__ src, const int* __restrict__ dst,
    const int* __restrict__ boffs, const int* __restrict__ bscan,
    unsigned* __restrict__ tmp)
{
    __shared__ int cur[NBUK];
    int bid = blockIdx.x, tid = threadIdx.x;
    for (int t = tid; t < NBUK; t += 256) cur[t] = 0;
    __syncthreads();
    for (int i = tid; i < EPB2; i += 256) {
        int e = bid * EPB2 + i;
        if (e < N_EDGES) {
            int d = dst[e];
            int s = src[e];
            int j = d >> 8;
            int r = atomicAdd(&cur[j], 1);
            int pos = boffs[(size_t)j * NSB2 + bid] + bscan[j] + r;
            tmp[pos] = ((unsigned)(d & 255) << 17) | (unsigned)s;
        }
    }
}

// ============================================================
// bucket_sort: one block per bucket (256 nodes); counting sort by dst
//   low 8 bits in LDS; emits sorted_src (src*128 byte offsets) + CSR offs
// ============================================================
__global__ __launch_bounds__(256) void bucket_sort(
    const unsigned* __restrict__ tmp, const int* __restrict__ bscan,
    int* __restrict__ sorted_src, int* __restrict__ offs)
{
    int bid = blockIdx.x, tid = threadIdx.x;
    int base = bscan[bid];
    int next = (bid == NBUK - 1) ? N_EDGES : bscan[bid + 1];
    int cnt = next - base;

    __shared__ int h[256];
    __shared__ int sc[256];
    __shared__ int o_[256];

    h[tid] = 0;
    __syncthreads();
    for (int i = tid; i < cnt; i += 256)
        atomicAdd(&h[tmp[base + i] >> 17], 1);
    __syncthreads();

    int x = h[tid];
    sc[tid] = x;
    __syncthreads();
    #pragma unroll
    for (int o = 1; o < 256; o <<= 1) {
        int t = (tid >= o) ? sc[tid - o] : 0;
        __syncthreads();
        sc[tid] += t;
        __syncthreads();
    }
    int excl = sc[tid] - x;
    o_[tid] = excl;
    int n = bid * 256 + tid;
    if (n < N_NODES) offs[n] = base + excl;
    __syncthreads();

    for (int i = tid; i < cnt; i += 256) {
        unsigned rec = tmp[base + i];
        int r = atomicAdd(&o_[rec >> 17], 1);
        sorted_src[base + r] = (int)((rec & 0x1FFFFu) << 7);  // src*128
    }
}

// ============================================================
// MFMA GEMM v2: LDS-staged A, LDS-staged epilogue, coalesced I/O
//   block = 32 rows; 4 waves, wave = matrix (0=q,1=k,2=v,3=skip)
//   Outputs: q8[n] 128B fp8 | vh[n] 128 half | ks_[n] k||skip 256 half
// ============================================================
__global__ __launch_bounds__(256) void gemm_mfma(
    const float* __restrict__ feat, const unsigned short* __restrict__ Wtb,
    const float* __restrict__ bq, const float* __restrict__ bk,
    const float* __restrict__ bv, const float* __restrict__ bs,
    unsigned char* __restrict__ q8, __half* __restrict__ vh,
    __half* __restrict__ ks_)
{
    __shared__ __align__(16) unsigned short Atile[32][136];   // 272 B rows
    __shared__ __align__(16) unsigned char  Oq8[32][144];     // 128 used
    __shared__ __align__(16) unsigned char  Ovh[32][272];     // 256 used
    __shared__ __align__(16) unsigned char  Oks[32][528];     // 512 used

    const int tid = threadIdx.x;
    const int r0  = blockIdx.x * 32;     // 3125 * 32 = 100000 exact

    {
        int row = tid >> 3;
        int cg  = (tid & 7) * 16;
        const float4* fp = (const float4*)(feat + (size_t)(r0 + row) * 128 + cg);
        float4 f0 = fp[0], f1 = fp[1], f2 = fp[2], f3 = fp[3];
        unsigned short* ap = &Atile[row][cg];
        ap[0]  = (unsigned short)f2bf_s(f0.x); ap[1]  = (unsigned short)f2bf_s(f0.y);
        ap[2]  = (unsigned short)f2bf_s(f0.z); ap[3]  = (unsigned short)f2bf_s(f0.w);
        ap[4]  = (unsigned short)f2bf_s(f1.x); ap[5]  = (unsigned short)f2bf_s(f1.y);
        ap[6]  = (unsigned short)f2bf_s(f1.z); ap[7]  = (unsigned short)f2bf_s(f1.w);
        ap[8]  = (unsigned short)f2bf_s(f2.x); ap[9]  = (unsigned short)f2bf_s(f2.y);
        ap[10] = (unsigned short)f2bf_s(f2.z); ap[11] = (unsigned short)f2bf_s(f2.w);
        ap[12] = (unsigned short)f2bf_s(f3.x); ap[13] = (unsigned short)f2bf_s(f3.y);
        ap[14] = (unsigned short)f2bf_s(f3.z); ap[15] = (unsigned short)f2bf_s(f3.w);
    }
    __syncthreads();

    const int mat = tid >> 6;
    const int l   = tid & 63;
    const int lr  = l & 15;
    const int lg  = l >> 4;
    const float* bias = (mat == 0) ? bq : (mat == 1) ? bk : (mat == 2) ? bv : bs;

    f32x4 acc[2][8];
    #pragma unroll
    for (int i = 0; i < 2; i++)
        #pragma unroll
        for (int j = 0; j < 8; j++) acc[i][j] = (f32x4){0.f, 0.f, 0.f, 0.f};

    #pragma unroll
    for (int kks = 0; kks < 4; kks++) {
        const int k0 = kks * 32 + lg * 8;
        bf16x8 a[2], b[8];
        #pragma unroll
        for (int rf = 0; rf < 2; rf++)
            a[rf] = *(const bf16x8*)&Atile[rf * 16 + lr][k0];
        #pragma unroll
        for (int cf = 0; cf < 8; cf++) {
            int col = cf * 16 + lr;
            b[cf] = *(const bf16x8*)(Wtb + ((size_t)mat * 128 + col) * 128 + k0);
        }
        #pragma unroll
        for (int rf = 0; rf < 2; rf++)
            #pragma unroll
            for (int cf = 0; cf < 8; cf++)
                acc[rf][cf] = __builtin_amdgcn_mfma_f32_16x16x32_bf16(
                    b[cf], a[rf], acc[rf][cf], 0, 0, 0);
    }

    #pragma unroll
    for (int rf = 0; rf < 2; rf++) {
        int rl = rf * 16 + lr;
        #pragma unroll
        for (int cf = 0; cf < 8; cf++) {
            int colb = cf * 16 + lg * 4;
            float4 b4 = *(const float4*)(bias + colb);
            float a0 = acc[rf][cf][0] + b4.x, a1 = acc[rf][cf][1] + b4.y;
            float a2 = acc[rf][cf][2] + b4.z, a3 = acc[rf][cf][3] + b4.w;
            if (mat == 0) {
                unsigned u = (unsigned)__builtin_amdgcn_cvt_pk_fp8_f32(a0, a1, 0, false);
                u = (unsigned)__builtin_amdgcn_cvt_pk_fp8_f32(a2, a3, (int)u, true);
                *(unsigned*)&Oq8[rl][colb] = u;
            } else if (mat == 2) {
                uint2 pk; pk.x = pack2h(a0, a1); pk.y = pack2h(a2, a3);
                *(uint2*)&Ovh[rl][colb * 2] = pk;
            } else {
                uint2 pk; pk.x = pack2h(a0, a1); pk.y = pack2h(a2, a3);
                *(uint2*)&Oks[rl][((mat == 3) ? 256 : 0) + colb * 2] = pk;
            }
        }
    }
    __syncthreads();

    {
        int row = tid >> 3;
        int c16 = (tid & 7) * 16;
        *(uint4*)(q8 + (size_t)(r0 + row) * 128 + c16) = *(const uint4*)&Oq8[row][c16];
        {
            char* gp = (char*)vh + (size_t)(r0 + row) * 256 + (tid & 7) * 32;
            const char* lp = (const char*)&Ovh[row][0] + (tid & 7) * 32;
            ((uint4*)gp)[0] = ((const uint4*)lp)[0];
            ((uint4*)gp)[1] = ((const uint4*)lp)[1];
        }
        {
            char* gp = (char*)ks_ + (size_t)(r0 + row) * 512 + (tid & 7) * 64;
            const char* lp = (const char*)&Oks[row][0] + (tid & 7) * 64;
            ((uint4*)gp)[0] = ((const uint4*)lp)[0];
            ((uint4*)gp)[1] = ((const uint4*)lp)[1];
            ((uint4*)gp)[2] = ((const uint4*)lp)[2];
            ((uint4*)gp)[3] = ((const uint4*)lp)[3];
        }
    }
}

// ============================================================
// fused dst-centric aggregation + gate + LN + PReLU
//   one wave per node; quarter-wave per edge; per edge: uint2 fp8 q gather
//   + uint4 fp16 v gather (384B/edge); depth-3 pipeline, decoupled idx loads
// ============================================================
__global__ __launch_bounds__(256) void node_fused(
    const unsigned char* __restrict__ q8, const __half* __restrict__ vh,
    const __half* __restrict__ ks_,
    const int* __restrict__ offs, const int* __restrict__ sorted_src,
    const float* __restrict__ wg, const float* __restrict__ bg,
    const float* __restrict__ gamma, const float* __restrict__ beta,
    const float* __restrict__ pa, float* __restrict__ out)
{
    int wid = threadIdx.x >> 6;
    int l   = threadIdx.x & 63;
    int qtr = l >> 4;
    int c   = l & 15;
    int n = blockIdx.x * 4 + wid;
    if (n >= N_NODES) return;

    int start = offs[n];
    int end   = (n + 1 < N_NODES) ? offs[n + 1] : N_EDGES;

    const uint4* krow = (const uint4*)ks_;
    uint4 kp  = krow[(size_t)n * 32 + c];
    uint4 sp4 = krow[(size_t)n * 32 + 16 + c];

    float kf[8];
    {
        __half2 h;
        h = bc2(kp.x); kf[0] = __low2float(h); kf[1] = __high2float(h);
        h = bc2(kp.y); kf[2] = __low2float(h); kf[3] = __high2float(h);
        h = bc2(kp.z); kf[4] = __low2float(h); kf[5] = __high2float(h);
        h = bc2(kp.w); kf[6] = __low2float(h); kf[7] = __high2float(h);
    }

    float den = 0.f;
    __half2 ag0 = bc2(0u), ag1 = bc2(0u), ag2 = bc2(0u), ag3 = bc2(0u);
    const float C = 0.25503483f;   // (1/sqrt(32)) * log2(e)

    const char* qb = (const char*)q8 + c * 8;     // + src*128
    const char* vb = (const char*)vh + c * 16;    // + src*256

    int base = start;
    int sA = sorted_src[min(base + qtr, end - 1)];
    uint2 qA = *(const uint2*)(qb + sA);
    uint4 vA = *(const uint4*)(vb + 2 * (size_t)sA);
    bool hasB = (base + 4) < end;
    uint2 qB; uint4 vB;
    if (hasB) {
        int sB = sorted_src[min(base + 4 + qtr, end - 1)];
        qB = *(const uint2*)(qb + sB);
        vB = *(const uint4*)(vb + 2 * (size_t)sB);
    }
    int sC = ((base + 8) < end) ? sorted_src[min(base + 8 + qtr, end - 1)] : 0;

    for (;;) {
        bool hasC = (base + 8) < end;
        uint2 qC; uint4 vC;
        if (hasC) {
            qC = *(const uint2*)(qb + sC);
            vC = *(const uint4*)(vb + 2 * (size_t)sC);
        }
        int sD = ((base + 12) < end) ? sorted_src[min(base + 12 + qtr, end - 1)] : 0;

        f32x2 q01 = __builtin_amdgcn_cvt_pk_f32_fp8((int)qA.x, false);
        f32x2 q23 = __builtin_amdgcn_cvt_pk_f32_fp8((int)qA.x, true);
        f32x2 q45 = __builtin_amdgcn_cvt_pk_f32_fp8((int)qA.y, false);
        f32x2 q67 = __builtin_amdgcn_cvt_pk_f32_fp8((int)qA.y, true);
        float d = q01.x * kf[0] + q01.y * kf[1] + q23.x * kf[2] + q23.y * kf[3]
                + q45.x * kf[4] + q45.y * kf[5] + q67.x * kf[6] + q67.y * kf[7];
        d += __shfl_xor(d, 1);
        d += __shfl_xor(d, 2);
        float e = (base + qtr < end) ? __builtin_amdgcn_exp2f(d * C) : 0.f;
        den += e;
        __half2 e2 = __float2half2_rn(e);
        ag0 = __hfma2(e2, bc2(vA.x), ag0);
        ag1 = __hfma2(e2, bc2(vA.y), ag1);
        ag2 = __hfma2(e2, bc2(vA.z), ag2);
        ag3 = __hfma2(e2, bc2(vA.w), ag3);

        if (!hasB) break;
        base += 4;
        qA = qB; vA = vB; qB = qC; vB = vC; sC = sD; hasB = hasC;
    }

    den += __shfl_xor(den, 16);
    den += __shfl_xor(den, 32);
    ag0 = __hadd2(ag0, bc2(__shfl_xor(bcu(ag0), 16)));
    ag1 = __hadd2(ag1, bc2(__shfl_xor(bcu(ag1), 16)));
    ag2 = __hadd2(ag2, bc2(__shfl_xor(bcu(ag2), 16)));
    ag3 = __hadd2(ag3, bc2(__shfl_xor(bcu(ag3), 16)));
    ag0 = __hadd2(ag0, bc2(__shfl_xor(bcu(ag0), 32)));
    ag1 = __hadd2(ag1, bc2(__shfl_xor(bcu(ag1), 32)));
    ag2 = __hadd2(ag2, bc2(__shfl_xor(bcu(ag2), 32)));
    ag3 = __hadd2(ag3, bc2(__shfl_xor(bcu(ag3), 32)));

    float rd = 1.f / den;
    float r[8];
    r[0] = __low2float(ag0) * rd; r[1] = __high2float(ag0) * rd;
    r[2] = __low2float(ag1) * rd; r[3] = __high2float(ag1) * rd;
    r[4] = __low2float(ag2) * rd; r[5] = __high2float(ag2) * rd;
    r[6] = __low2float(ag3) * rd; r[7] = __high2float(ag3) * rd;

    float s[8];
    s[0] = __low2float(bc2(sp4.x)); s[1] = __high2float(bc2(sp4.x));
    s[2] = __low2float(bc2(sp4.y)); s[3] = __high2float(bc2(sp4.y));
    s[4] = __low2float(bc2(sp4.z)); s[5] = __high2float(bc2(sp4.z));
    s[6] = __low2float(bc2(sp4.w)); s[7] = __high2float(bc2(sp4.w));

    const float4* wgf = (const float4*)wg;
    float4 w0a = wgf[2 * c],      w0b = wgf[2 * c + 1];
    float4 w1a = wgf[32 + 2 * c], w1b = wgf[32 + 2 * c + 1];
    float4 w2a = wgf[64 + 2 * c], w2b = wgf[64 + 2 * c + 1];
    float w0[8] = {w0a.x, w0a.y, w0a.z, w0a.w, w0b.x, w0b.y, w0b.z, w0b.w};
    float w1[8] = {w1a.x, w1a.y, w1a.z, w1a.w, w1b.x, w1b.y, w1b.z, w1b.w};
    float w2[8] = {w2a.x, w2a.y, w2a.z, w2a.w, w2b.x, w2b.y, w2b.z, w2b.w};

    float gs = 0.f;
    #pragma unroll
    for (int j = 0; j < 8; j++)
        gs += s[j] * w0[j] + r[j] * w1[j] + (s[j] - r[j]) * w2[j];
    gs += __shfl_xor(gs, 1);
    gs += __shfl_xor(gs, 2);
    gs += __shfl_xor(gs, 4);
    gs += __shfl_xor(gs, 8);
    float g = 1.f / (1.f + __builtin_amdgcn_exp2f(-(gs + bg[0]) * 1.4426950408889634f));

    #pragma unroll
    for (int j = 0; j < 8; j++) r[j] = g * s[j] + (1.f - g) * r[j];

    float mu = 0.f;
    #pragma unroll
    for (int j = 0; j < 8; j++) mu += r[j];
    mu += __shfl_xor(mu, 1);
    mu += __shfl_xor(mu, 2);
    mu += __shfl_xor(mu, 4);
    mu += __shfl_xor(mu, 8);
    mu *= (1.f / 128.f);

    float var = 0.f;
    #pragma unroll
    for (int j = 0; j < 8; j++) { float e0 = r[j] - mu; var += e0 * e0; }
    var += __shfl_xor(var, 1);
    var += __shfl_xor(var, 2);
    var += __shfl_xor(var, 4);
    var += __shfl_xor(var, 8);
    var *= (1.f / 128.f);
    float inv = rsqrtf(var + 1e-5f);

    if (qtr == 0) {
        float4 ga = ((const float4*)gamma)[2 * c], gb = ((const float4*)gamma)[2 * c + 1];
        float4 ba = ((const float4*)beta)[2 * c],  bb = ((const float4*)beta)[2 * c + 1];
        float gm[8] = {ga.x, ga.y, ga.z, ga.w, gb.x, gb.y, gb.z, gb.w};
        float bt[8] = {ba.x, ba.y, ba.z, ba.w, bb.x, bb.y, bb.z, bb.w};
        float al = pa[0];
        float y[8];
        #pragma unroll
        for (int j = 0; j < 8; j++) {
            float t = (r[j] - mu) * inv * gm[j] + bt[j];
            y[j] = (t > 0.f) ? t : al * t;
        }
        float4* op = (float4*)(out + (size_t)n * 128 + c * 8);
        op[0] = (float4){y[0], y[1], y[2], y[3]};
        op[1] = (float4){y[4], y[5], y[6], y[7]};
    }
}

// ============================================================
extern "C" void kernel_launch(void* const* d_in, const int* in_sizes, int n_in,
                              void* d_out, int out_size, void* d_ws, size_t ws_size,
                              hipStream_t stream) {
    const float* feat  = (const float*)d_in[0];
    const int*   src   = (const int*)d_in[1];
    const int*   dst   = (const int*)d_in[2];
    const float* Wq    = (const float*)d_in[3];
    const float* bq    = (const float*)d_in[4];
    const float* Wk    = (const float*)d_in[5];
    const float* bk    = (const float*)d_in[6];
    const float* Wv    = (const float*)d_in[7];
    const float* bv    = (const float*)d_in[8];
    const float* Wsk   = (const float*)d_in[9];
    const float* bsk   = (const float*)d_in[10];
    const float* Wg    = (const float*)d_in[11];
    const float* bg    = (const float*)d_in[12];
    const float* gamma = (const float*)d_in[13];
    const float* beta  = (const float*)d_in[14];
    const float* pa    = (const float*)d_in[15];
    float* out = (float*)d_out;

    char* p = (char*)d_ws;
    unsigned char* q8  = (unsigned char*)p;  p += (size_t)N_NODES * 128;       // 12.8 MB
    __half*        vh  = (__half*)p;         p += (size_t)N_NODES * 128 * 2;   // 25.6 MB
    __half*        ks_ = (__half*)p;         p += (size_t)N_NODES * 256 * 2;   // 51.2 MB
    unsigned short* Wtb = (unsigned short*)p;  p += (size_t)4 * 128 * 128 * 2;
    int*      sorted_src = (int*)p;      p += (size_t)N_EDGES * 4;
    unsigned* tmp        = (unsigned*)p; p += (size_t)N_EDGES * 4;
    int*      histT      = (int*)p;      p += (size_t)NBUK * NSB2 * 4;   // 1.6 MB
    int*      boffs      = (int*)p;      p += (size_t)NBUK * NSB2 * 4;   // 1.6 MB
    int*      offs       = (int*)p;      p += (size_t)N_NODES * 4;
    int*      bsums      = (int*)p;      p += 4096;
    int*      bscan      = (int*)p;      p += 4096;

    hist2_wt<<<NSB2 + 256, 256, 0, stream>>>(dst, Wq, Wk, Wv, Wsk, histT, Wtb);
    scan_block2<<<NBUK, 256, 0, stream>>>(histT, boffs, bsums);
    scan_sums2<<<1, 512, 0, stream>>>(bsums, bscan);
    scatter2<<<NSB2, 256, 0, stream>>>(src, dst, boffs, bscan, tmp);
    bucket_sort<<<NBUK, 256, 0, stream>>>(tmp, bscan, sorted_src, offs);
    gemm_mfma<<<3125, 256, 0, stream>>>(feat, Wtb, bq, bk, bv, bsk, q8, vh, ks_);
    node_fused<<<(N_NODES + 3) / 4, 256, 0, stream>>>(q8, vh, ks_, offs, sorted_src,
                                                      Wg, bg, gamma, beta, pa, out);
}

// Round 16
// 233.832 us; speedup vs baseline: 1.3759x; 1.0308x over previous
//
#include <hip/hip_runtime.h>
#include <hip/hip_bf16.h>
#include <hip/hip_fp16.h>
#include <math.h>

#define N_NODES 100000
#define N_EDGES 1600000
#define NBUK 196          // buckets = dst>>9 ; 99999>>9 = 195
#define NSB  256          // hist/scatter blocks
#define EPB  6250         // edges per block (256*6250 = 1.6M exact)
// IN=128, HD=128, H=4, D=32

typedef __attribute__((ext_vector_type(8))) short bf16x8;
typedef __attribute__((ext_vector_type(4))) float f32x4;
typedef __attribute__((ext_vector_type(2))) float f32x2;

__device__ __forceinline__ short f2bf_s(float x) {
    __hip_bfloat16 b = __float2bfloat16(x);
    return *reinterpret_cast<short*>(&b);
}
__device__ __forceinline__ __half2 bc2(unsigned u) {
    return *reinterpret_cast<__half2*>(&u);
}
__device__ __forceinline__ unsigned bcu(__half2 h) {
    return *reinterpret_cast<unsigned*>(&h);
}
__device__ __forceinline__ unsigned pack2h(float a, float b) {
    __half ha = __float2half(a), hb = __float2half(b);
    return (unsigned)*reinterpret_cast<unsigned short*>(&ha)
         | ((unsigned)*reinterpret_cast<unsigned short*>(&hb) << 16);
}

// ============================================================
// hist2_wt: blocks 0..255 = per-block bucket histogram (per-wave LDS copies)
//           blocks 256..511 = W transpose -> bf16
//   histT layout: [bucket][block]
// ============================================================
__global__ __launch_bounds__(256) void hist2_wt(
    const int* __restrict__ dst,
    const float* __restrict__ Wq, const float* __restrict__ Wk,
    const float* __restrict__ Wv, const float* __restrict__ Ws,
    int* __restrict__ histT, unsigned short* __restrict__ Wtb)
{
    int bid = blockIdx.x, tid = threadIdx.x;
    if (bid < NSB) {
        __shared__ int h[4 * NBUK];
        for (int t = tid; t < 4 * NBUK; t += 256) h[t] = 0;
        __syncthreads();
        int w = tid >> 6;
        for (int i = tid; i < EPB; i += 256)
            atomicAdd(&h[w * NBUK + (dst[bid * EPB + i] >> 9)], 1);
        __syncthreads();
        if (tid < NBUK)
            histT[tid * NSB + bid] = h[tid] + h[NBUK + tid]
                                   + h[2 * NBUK + tid] + h[3 * NBUK + tid];
    } else {
        int j = (bid - NSB) * 256 + tid;   // [0, 65536)
        int m = j >> 14;
        int rem = j & 16383;
        int c = rem >> 7;
        int kk = rem & 127;
        const float* W = (m == 0) ? Wq : (m == 1) ? Wk : (m == 2) ? Wv : Ws;
        Wtb[j] = (unsigned short)f2bf_s(W[(size_t)kk * 128 + c]);
    }
}

// ============================================================
// scan_block2: grid = NBUK; block b scans histT[b][0..255] -> boffs
//   (exclusive within bucket), bsums[b] = bucket total
// ============================================================
__global__ __launch_bounds__(256) void scan_block2(
    const int* __restrict__ in, int* __restrict__ outlocal, int* __restrict__ bsums)
{
    __shared__ int s[256];
    int i = blockIdx.x * 256 + threadIdx.x;
    int x = in[i];
    s[threadIdx.x] = x;
    __syncthreads();
    #pragma unroll
    for (int o = 1; o < 256; o <<= 1) {
        int t = (threadIdx.x >= o) ? s[threadIdx.x - o] : 0;
        __syncthreads();
        s[threadIdx.x] += t;
        __syncthreads();
    }
    outlocal[i] = s[threadIdx.x] - x;
    if (threadIdx.x == 255) bsums[blockIdx.x] = s[255];
}

// ============================================================
// scatter2: edges -> bucket-contiguous tmp; bucket bases (bscan) computed
//   IN-BLOCK from bsums (196-entry LDS scan) — no scan_sums2 launch
//   rec = (dst&511)<<17 | src   (src < 2^17)
// ============================================================
__global__ __launch_bounds__(256) void scatter2(
    const int* __restrict__ src, const int* __restrict__ dst,
    const int* __restrict__ boffs, const int* __restrict__ bsums,
    unsigned* __restrict__ tmp)
{
    __shared__ int cur[NBUK];
    __shared__ int bsc[NBUK];
    __shared__ int s[256];
    int bid = blockIdx.x, tid = threadIdx.x;
    if (tid < NBUK) cur[tid] = 0;
    int x = (tid < NBUK) ? bsums[tid] : 0;
    s[tid] = x;
    __syncthreads();
    #pragma unroll
    for (int o = 1; o < 256; o <<= 1) {
        int t = (tid >= o) ? s[tid - o] : 0;
        __syncthreads();
        s[tid] += t;
        __syncthreads();
    }
    if (tid < NBUK) bsc[tid] = s[tid] - x;   // exclusive bucket base
    __syncthreads();

    for (int i = tid; i < EPB; i += 256) {
        int e = bid * EPB + i;
        int d = dst[e];
        int sv = src[e];
        int j = d >> 9;
        int r = atomicAdd(&cur[j], 1);
        int pos = boffs[j * NSB + bid] + bsc[j] + r;
        tmp[pos] = ((unsigned)(d & 511) << 17) | (unsigned)sv;
    }
}

// ============================================================
// bucket_sort: one block per bucket (512 nodes); counting sort by dst low
//   9 bits in LDS; bucket base computed in-block from bsums; emits
//   sorted_src (src*128 byte offsets) + CSR offs
// ============================================================
__global__ __launch_bounds__(256) void bucket_sort(
    const unsigned* __restrict__ tmp, const int* __restrict__ bsums,
    int* __restrict__ sorted_src, int* __restrict__ offs)
{
    int bid = blockIdx.x, tid = threadIdx.x;

    __shared__ int h[512];
    __shared__ int o_[512];
    __shared__ int s_[256];
    __shared__ int baseSh;

    // bucket base = exclusive scan of bsums at index bid
    int x = (tid < NBUK) ? bsums[tid] : 0;
    s_[tid] = x;
    __syncthreads();
    #pragma unroll
    for (int o = 1; o < 256; o <<= 1) {
        int t = (tid >= o) ? s_[tid - o] : 0;
        __syncthreads();
        s_[tid] += t;
        __syncthreads();
    }
    if (tid == bid) baseSh = s_[tid] - x;
    h[tid] = 0; h[tid + 256] = 0;
    __syncthreads();
    int base = baseSh;
    int cnt  = bsums[bid];

    for (int i = tid; i < cnt; i += 256)
        atomicAdd(&h[tmp[base + i] >> 17], 1);
    __syncthreads();

    int a0 = h[2 * tid], a1 = h[2 * tid + 1];
    s_[tid] = a0 + a1;
    __syncthreads();
    #pragma unroll
    for (int o = 1; o < 256; o <<= 1) {
        int t = (tid >= o) ? s_[tid - o] : 0;
        __syncthreads();
        s_[tid] += t;
        __syncthreads();
    }
    int eb = s_[tid] - a0 - a1;
    o_[2 * tid] = eb;
    o_[2 * tid + 1] = eb + a0;
    __syncthreads();

    for (int t = tid; t < 512; t += 256) {
        int n = bid * 512 + t;
        if (n < N_NODES) offs[n] = base + o_[t];
    }
    __syncthreads();

    for (int i = tid; i < cnt; i += 256) {
        unsigned rec = tmp[base + i];
        int r = atomicAdd(&o_[rec >> 17], 1);
        sorted_src[base + r] = (int)((rec & 0x1FFFFu) << 7);  // src*128
    }
}

// ============================================================
// MFMA GEMM v2: LDS-staged A, LDS-staged epilogue, coalesced I/O
//   block = 32 rows; 4 waves, wave = matrix (0=q,1=k,2=v,3=skip)
//   Outputs: q8[n] 128B fp8 | vh[n] 128 half | ks_[n] k||skip 256 half
// ============================================================
__global__ __launch_bounds__(256) void gemm_mfma(
    const float* __restrict__ feat, const unsigned short* __restrict__ Wtb,
    const float* __restrict__ bq, const float* __restrict__ bk,
    const float* __restrict__ bv, const float* __restrict__ bs,
    unsigned char* __restrict__ q8, __half* __restrict__ vh,
    __half* __restrict__ ks_)
{
    __shared__ __align__(16) unsigned short Atile[32][136];   // 272 B rows
    __shared__ __align__(16) unsigned char  Oq8[32][144];     // 128 used
    __shared__ __align__(16) unsigned char  Ovh[32][272];     // 256 used
    __shared__ __align__(16) unsigned char  Oks[32][528];     // 512 used

    const int tid = threadIdx.x;
    const int r0  = blockIdx.x * 32;     // 3125 * 32 = 100000 exact

    {
        int row = tid >> 3;
        int cg  = (tid & 7) * 16;
        const float4* fp = (const float4*)(feat + (size_t)(r0 + row) * 128 + cg);
        float4 f0 = fp[0], f1 = fp[1], f2 = fp[2], f3 = fp[3];
        unsigned short* ap = &Atile[row][cg];
        ap[0]  = (unsigned short)f2bf_s(f0.x); ap[1]  = (unsigned short)f2bf_s(f0.y);
        ap[2]  = (unsigned short)f2bf_s(f0.z); ap[3]  = (unsigned short)f2bf_s(f0.w);
        ap[4]  = (unsigned short)f2bf_s(f1.x); ap[5]  = (unsigned short)f2bf_s(f1.y);
        ap[6]  = (unsigned short)f2bf_s(f1.z); ap[7]  = (unsigned short)f2bf_s(f1.w);
        ap[8]  = (unsigned short)f2bf_s(f2.x); ap[9]  = (unsigned short)f2bf_s(f2.y);
        ap[10] = (unsigned short)f2bf_s(f2.z); ap[11] = (unsigned short)f2bf_s(f2.w);
        ap[12] = (unsigned short)f2bf_s(f3.x); ap[13] = (unsigned short)f2bf_s(f3.y);
        ap[14] = (unsigned short)f2bf_s(f3.z); ap[15] = (unsigned short)f2bf_s(f3.w);
    }
    __syncthreads();

    const int mat = tid >> 6;
    const int l   = tid & 63;
    const int lr  = l & 15;
    const int lg  = l >> 4;
    const float* bias = (mat == 0) ? bq : (mat == 1) ? bk : (mat == 2) ? bv : bs;

    f32x4 acc[2][8];
    #pragma unroll
    for (int i = 0; i < 2; i++)
        #pragma unroll
        for (int j = 0; j < 8; j++) acc[i][j] = (f32x4){0.f, 0.f, 0.f, 0.f};

    #pragma unroll
    for (int kks = 0; kks < 4; kks++) {
        const int k0 = kks * 32 + lg * 8;
        bf16x8 a[2], b[8];
        #pragma unroll
        for (int rf = 0; rf < 2; rf++)
            a[rf] = *(const bf16x8*)&Atile[rf * 16 + lr][k0];
        #pragma unroll
        for (int cf = 0; cf < 8; cf++) {
            int col = cf * 16 + lr;
            b[cf] = *(const bf16x8*)(Wtb + ((size_t)mat * 128 + col) * 128 + k0);
        }
        #pragma unroll
        for (int rf = 0; rf < 2; rf++)
            #pragma unroll
            for (int cf = 0; cf < 8; cf++)
                acc[rf][cf] = __builtin_amdgcn_mfma_f32_16x16x32_bf16(
                    b[cf], a[rf], acc[rf][cf], 0, 0, 0);
    }

    #pragma unroll
    for (int rf = 0; rf < 2; rf++) {
        int rl = rf * 16 + lr;
        #pragma unroll
        for (int cf = 0; cf < 8; cf++) {
            int colb = cf * 16 + lg * 4;
            float4 b4 = *(const float4*)(bias + colb);
            float a0 = acc[rf][cf][0] + b4.x, a1 = acc[rf][cf][1] + b4.y;
            float a2 = acc[rf][cf][2] + b4.z, a3 = acc[rf][cf][3] + b4.w;
            if (mat == 0) {
                unsigned u = (unsigned)__builtin_amdgcn_cvt_pk_fp8_f32(a0, a1, 0, false);
                u = (unsigned)__builtin_amdgcn_cvt_pk_fp8_f32(a2, a3, (int)u, true);
                *(unsigned*)&Oq8[rl][colb] = u;
            } else if (mat == 2) {
                uint2 pk; pk.x = pack2h(a0, a1); pk.y = pack2h(a2, a3);
                *(uint2*)&Ovh[rl][colb * 2] = pk;
            } else {
                uint2 pk; pk.x = pack2h(a0, a1); pk.y = pack2h(a2, a3);
                *(uint2*)&Oks[rl][((mat == 3) ? 256 : 0) + colb * 2] = pk;
            }
        }
    }
    __syncthreads();

    {
        int row = tid >> 3;
        int c16 = (tid & 7) * 16;
        *(uint4*)(q8 + (size_t)(r0 + row) * 128 + c16) = *(const uint4*)&Oq8[row][c16];
        {
            char* gp = (char*)vh + (size_t)(r0 + row) * 256 + (tid & 7) * 32;
            const char* lp = (const char*)&Ovh[row][0] + (tid & 7) * 32;
            ((uint4*)gp)[0] = ((const uint4*)lp)[0];
            ((uint4*)gp)[1] = ((const uint4*)lp)[1];
        }
        {
            char* gp = (char*)ks_ + (size_t)(r0 + row) * 512 + (tid & 7) * 64;
            const char* lp = (const char*)&Oks[row][0] + (tid & 7) * 64;
            ((uint4*)gp)[0] = ((const uint4*)lp)[0];
            ((uint4*)gp)[1] = ((const uint4*)lp)[1];
            ((uint4*)gp)[2] = ((const uint4*)lp)[2];
            ((uint4*)gp)[3] = ((const uint4*)lp)[3];
        }
    }
}

// ============================================================
// fused dst-centric aggregation + gate + LN + PReLU
//   one wave per node; quarter-wave per edge; per edge: uint2 fp8 q gather
//   + uint4 fp16 v gather (384B/edge); depth-3 pipeline, decoupled idx loads
//   dot via packed f32x2 ops (v_pk_fma_f32)
// ============================================================
__global__ __launch_bounds__(256) void node_fused(
    const unsigned char* __restrict__ q8, const __half* __restrict__ vh,
    const __half* __restrict__ ks_,
    const int* __restrict__ offs, const int* __restrict__ sorted_src,
    const float* __restrict__ wg, const float* __restrict__ bg,
    const float* __restrict__ gamma, const float* __restrict__ beta,
    const float* __restrict__ pa, float* __restrict__ out)
{
    int wid = threadIdx.x >> 6;
    int l   = threadIdx.x & 63;
    int qtr = l >> 4;
    int c   = l & 15;
    int n = blockIdx.x * 4 + wid;
    if (n >= N_NODES) return;

    int start = offs[n];
    int end   = (n + 1 < N_NODES) ? offs[n + 1] : N_EDGES;

    const uint4* krow = (const uint4*)ks_;
    uint4 kp  = krow[(size_t)n * 32 + c];
    uint4 sp4 = krow[(size_t)n * 32 + 16 + c];

    f32x2 kp0, kp1, kp2, kp3;
    {
        __half2 h;
        h = bc2(kp.x); kp0 = (f32x2){__low2float(h), __high2float(h)};
        h = bc2(kp.y); kp1 = (f32x2){__low2float(h), __high2float(h)};
        h = bc2(kp.z); kp2 = (f32x2){__low2float(h), __high2float(h)};
        h = bc2(kp.w); kp3 = (f32x2){__low2float(h), __high2float(h)};
    }

    float den = 0.f;
    __half2 ag0 = bc2(0u), ag1 = bc2(0u), ag2 = bc2(0u), ag3 = bc2(0u);
    const float C = 0.25503483f;   // (1/sqrt(32)) * log2(e)

    const char* qb = (const char*)q8 + c * 8;     // + src*128
    const char* vb = (const char*)vh + c * 16;    // + src*256

    int base = start;
    int sA = sorted_src[min(base + qtr, end - 1)];
    uint2 qA = *(const uint2*)(qb + sA);
    uint4 vA = *(const uint4*)(vb + 2 * (size_t)sA);
    bool hasB = (base + 4) < end;
    uint2 qB; uint4 vB;
    if (hasB) {
        int sB = sorted_src[min(base + 4 + qtr, end - 1)];
        qB = *(const uint2*)(qb + sB);
        vB = *(const uint4*)(vb + 2 * (size_t)sB);
    }
    int sC = ((base + 8) < end) ? sorted_src[min(base + 8 + qtr, end - 1)] : 0;

    for (;;) {
        bool hasC = (base + 8) < end;
        uint2 qC; uint4 vC;
        if (hasC) {
            qC = *(const uint2*)(qb + sC);
            vC = *(const uint4*)(vb + 2 * (size_t)sC);
        }
        int sD = ((base + 12) < end) ? sorted_src[min(base + 12 + qtr, end - 1)] : 0;

        // score: fp8 q decode + packed f32x2 dot with k
        f32x2 q01 = __builtin_amdgcn_cvt_pk_f32_fp8((int)qA.x, false);
        f32x2 q23 = __builtin_amdgcn_cvt_pk_f32_fp8((int)qA.x, true);
        f32x2 q45 = __builtin_amdgcn_cvt_pk_f32_fp8((int)qA.y, false);
        f32x2 q67 = __builtin_amdgcn_cvt_pk_f32_fp8((int)qA.y, true);
        f32x2 d2 = q01 * kp0 + q23 * kp1 + q45 * kp2 + q67 * kp3;
        float d = d2[0] + d2[1];
        d += __shfl_xor(d, 1);
        d += __shfl_xor(d, 2);
        float e = (base + qtr < end) ? __builtin_amdgcn_exp2f(d * C) : 0.f;
        den += e;
        __half2 e2 = __float2half2_rn(e);
        ag0 = __hfma2(e2, bc2(vA.x), ag0);
        ag1 = __hfma2(e2, bc2(vA.y), ag1);
        ag2 = __hfma2(e2, bc2(vA.z), ag2);
        ag3 = __hfma2(e2, bc2(vA.w), ag3);

        if (!hasB) break;
        base += 4;
        qA = qB; vA = vB; qB = qC; vB = vC; sC = sD; hasB = hasC;
    }

    den += __shfl_xor(den, 16);
    den += __shfl_xor(den, 32);
    ag0 = __hadd2(ag0, bc2(__shfl_xor(bcu(ag0), 16)));
    ag1 = __hadd2(ag1, bc2(__shfl_xor(bcu(ag1), 16)));
    ag2 = __hadd2(ag2, bc2(__shfl_xor(bcu(ag2), 16)));
    ag3 = __hadd2(ag3, bc2(__shfl_xor(bcu(ag3), 16)));
    ag0 = __hadd2(ag0, bc2(__shfl_xor(bcu(ag0), 32)));
    ag1 = __hadd2(ag1, bc2(__shfl_xor(bcu(ag1), 32)));
    ag2 = __hadd2(ag2, bc2(__shfl_xor(bcu(ag2), 32)));
    ag3 = __hadd2(ag3, bc2(__shfl_xor(bcu(ag3), 32)));

    float rd = 1.f / den;
    float r[8];
    r[0] = __low2float(ag0) * rd; r[1] = __high2float(ag0) * rd;
    r[2] = __low2float(ag1) * rd; r[3] = __high2float(ag1) * rd;
    r[4] = __low2float(ag2) * rd; r[5] = __high2float(ag2) * rd;
    r[6] = __low2float(ag3) * rd; r[7] = __high2float(ag3) * rd;

    float s[8];
    s[0] = __low2float(bc2(sp4.x)); s[1] = __high2float(bc2(sp4.x));
    s[2] = __low2float(bc2(sp4.y)); s[3] = __high2float(bc2(sp4.y));
    s[4] = __low2float(bc2(sp4.z)); s[5] = __high2float(bc2(sp4.z));
    s[6] = __low2float(bc2(sp4.w)); s[7] = __high2float(bc2(sp4.w));

    const float4* wgf = (const float4*)wg;
    float4 w0a = wgf[2 * c],      w0b = wgf[2 * c + 1];
    float4 w1a = wgf[32 + 2 * c], w1b = wgf[32 + 2 * c + 1];
    float4 w2a = wgf[64 + 2 * c], w2b = wgf[64 + 2 * c + 1];
    float w0[8] = {w0a.x, w0a.y, w0a.z, w0a.w, w0b.x, w0b.y, w0b.z, w0b.w};
    float w1[8] = {w1a.x, w1a.y, w1a.z, w1a.w, w1b.x, w1b.y, w1b.z, w1b.w};
    float w2[8] = {w2a.x, w2a.y, w2a.z, w2a.w, w2b.x, w2b.y, w2b.z, w2b.w};

    float gs = 0.f;
    #pragma unroll
    for (int j = 0; j < 8; j++)
        gs += s[j] * w0[j] + r[j] * w1[j] + (s[j] - r[j]) * w2[j];
    gs += __shfl_xor(gs, 1);
    gs += __shfl_xor(gs, 2);
    gs += __shfl_xor(gs, 4);
    gs += __shfl_xor(gs, 8);
    float g = 1.f / (1.f + __builtin_amdgcn_exp2f(-(gs + bg[0]) * 1.4426950408889634f));

    #pragma unroll
    for (int j = 0; j < 8; j++) r[j] = g * s[j] + (1.f - g) * r[j];

    float mu = 0.f;
    #pragma unroll
    for (int j = 0; j < 8; j++) mu += r[j];
    mu += __shfl_xor(mu, 1);
    mu += __shfl_xor(mu, 2);
    mu += __shfl_xor(mu, 4);
    mu += __shfl_xor(mu, 8);
    mu *= (1.f / 128.f);

    float var = 0.f;
    #pragma unroll
    for (int j = 0; j < 8; j++) { float e0 = r[j] - mu; var += e0 * e0; }
    var += __shfl_xor(var, 1);
    var += __shfl_xor(var, 2);
    var += __shfl_xor(var, 4);
    var += __shfl_xor(var, 8);
    var *= (1.f / 128.f);
    float inv = rsqrtf(var + 1e-5f);

    if (qtr == 0) {
        float4 ga = ((const float4*)gamma)[2 * c], gb = ((const float4*)gamma)[2 * c + 1];
        float4 ba = ((const float4*)beta)[2 * c],  bb = ((const float4*)beta)[2 * c + 1];
        float gm[8] = {ga.x, ga.y, ga.z, ga.w, gb.x, gb.y, gb.z, gb.w};
        float bt[8] = {ba.x, ba.y, ba.z, ba.w, bb.x, bb.y, bb.z, bb.w};
        float al = pa[0];
        float y[8];
        #pragma unroll
        for (int j = 0; j < 8; j++) {
            float t = (r[j] - mu) * inv * gm[j] + bt[j];
            y[j] = (t > 0.f) ? t : al * t;
        }
        float4* op = (float4*)(out + (size_t)n * 128 + c * 8);
        op[0] = (float4){y[0], y[1], y[2], y[3]};
        op[1] = (float4){y[4], y[5], y[6], y[7]};
    }
}

// ============================================================
extern "C" void kernel_launch(void* const* d_in, const int* in_sizes, int n_in,
                              void* d_out, int out_size, void* d_ws, size_t ws_size,
                              hipStream_t stream) {
    const float* feat  = (const float*)d_in[0];
    const int*   src   = (const int*)d_in[1];
    const int*   dst   = (const int*)d_in[2];
    const float* Wq    = (const float*)d_in[3];
    const float* bq    = (const float*)d_in[4];
    const float* Wk    = (const float*)d_in[5];
    const float* bk    = (const float*)d_in[6];
    const float* Wv    = (const float*)d_in[7];
    const float* bv    = (const float*)d_in[8];
    const float* Wsk   = (const float*)d_in[9];
    const float* bsk   = (const float*)d_in[10];
    const float* Wg    = (const float*)d_in[11];
    const float* bg    = (const float*)d_in[12];
    const float* gamma = (const float*)d_in[13];
    const float* beta  = (const float*)d_in[14];
    const float* pa    = (const float*)d_in[15];
    float* out = (float*)d_out;

    char* p = (char*)d_ws;
    unsigned char* q8  = (unsigned char*)p;  p += (size_t)N_NODES * 128;       // 12.8 MB
    __half*        vh  = (__half*)p;         p += (size_t)N_NODES * 128 * 2;   // 25.6 MB
    __half*        ks_ = (__half*)p;         p += (size_t)N_NODES * 256 * 2;   // 51.2 MB
    unsigned short* Wtb = (unsigned short*)p;  p += (size_t)4 * 128 * 128 * 2;
    int*      sorted_src = (int*)p;      p += (size_t)N_EDGES * 4;
    unsigned* tmp        = (unsigned*)p; p += (size_t)N_EDGES * 4;
    int*      histT      = (int*)p;      p += (size_t)NBUK * NSB * 4;
    int*      boffs      = (int*)p;      p += (size_t)NBUK * NSB * 4;
    int*      offs       = (int*)p;      p += (size_t)N_NODES * 4;
    int*      bsums      = (int*)p;      p += 4096;

    hist2_wt<<<NSB + 256, 256, 0, stream>>>(dst, Wq, Wk, Wv, Wsk, histT, Wtb);
    scan_block2<<<NBUK, 256, 0, stream>>>(histT, boffs, bsums);
    scatter2<<<NSB, 256, 0, stream>>>(src, dst, boffs, bsums, tmp);
    bucket_sort<<<NBUK, 256, 0, stream>>>(tmp, bsums, sorted_src, offs);
    gemm_mfma<<<3125, 256, 0, stream>>>(feat, Wtb, bq, bk, bv, bsk, q8, vh, ks_);
    node_fused<<<(N_NODES + 3) / 4, 256, 0, stream>>>(q8, vh, ks_, offs, sorted_src,
                                                      Wg, bg, gamma, beta, pa, out);
}

// Round 17
// 205.770 us; speedup vs baseline: 1.5636x; 1.1364x over previous
//
#include <hip/hip_runtime.h>
#include <hip/hip_bf16.h>
#include <hip/hip_fp16.h>
#include <math.h>

#define N_NODES 100000
#define N_EDGES 1600000
#define NBUK 196          // buckets = dst>>9 ; 99999>>9 = 195
#define NSB  256          // hist/scatter blocks
#define EPB  6250         // edges per block (256*6250 = 1.6M exact)
// IN=128, HD=128, H=4, D=32

typedef __attribute__((ext_vector_type(8))) short bf16x8;
typedef __attribute__((ext_vector_type(4))) float f32x4;
typedef __attribute__((ext_vector_type(2))) float f32x2;

__device__ __forceinline__ short f2bf_s(float x) {
    __hip_bfloat16 b = __float2bfloat16(x);
    return *reinterpret_cast<short*>(&b);
}
__device__ __forceinline__ __half2 bc2(unsigned u) {
    return *reinterpret_cast<__half2*>(&u);
}
__device__ __forceinline__ unsigned bcu(__half2 h) {
    return *reinterpret_cast<unsigned*>(&h);
}
__device__ __forceinline__ unsigned pack2h(float a, float b) {
    __half ha = __float2half(a), hb = __float2half(b);
    return (unsigned)*reinterpret_cast<unsigned short*>(&ha)
         | ((unsigned)*reinterpret_cast<unsigned short*>(&hb) << 16);
}

// ============================================================
// hist2_wt: blocks 0..255 = per-block bucket histogram (per-wave LDS copies)
//           blocks 256..511 = W -> bf16 in MFMA-fragment order:
//   Wtb[mat][kks][lg][cf][lr][j8] = W[kks*32+lg*8+j8][cf*16+lr]
//   (b[cf] load becomes 256B-contiguous across lanes lr=0..15)
// ============================================================
__global__ __launch_bounds__(256) void hist2_wt(
    const int* __restrict__ dst,
    const float* __restrict__ Wq, const float* __restrict__ Wk,
    const float* __restrict__ Wv, const float* __restrict__ Ws,
    int* __restrict__ histT, unsigned short* __restrict__ Wtb)
{
    int bid = blockIdx.x, tid = threadIdx.x;
    if (bid < NSB) {
        __shared__ int h[4 * NBUK];
        for (int t = tid; t < 4 * NBUK; t += 256) h[t] = 0;
        __syncthreads();
        int w = tid >> 6;
        for (int i = tid; i < EPB; i += 256)
            atomicAdd(&h[w * NBUK + (dst[bid * EPB + i] >> 9)], 1);
        __syncthreads();
        if (tid < NBUK)
            histT[tid * NSB + bid] = h[tid] + h[NBUK + tid]
                                   + h[2 * NBUK + tid] + h[3 * NBUK + tid];
    } else {
        int j = (bid - NSB) * 256 + tid;   // [0, 65536)
        int j8  = j & 7;
        int lr  = (j >> 3) & 15;
        int cf  = (j >> 7) & 7;
        int lg  = (j >> 10) & 3;
        int kks = (j >> 12) & 3;
        int m   = j >> 14;
        int k   = kks * 32 + lg * 8 + j8;
        int col = cf * 16 + lr;
        const float* W = (m == 0) ? Wq : (m == 1) ? Wk : (m == 2) ? Wv : Ws;
        Wtb[j] = (unsigned short)f2bf_s(W[(size_t)k * 128 + col]);
    }
}

// ============================================================
// scan_block2: grid = NBUK; block b scans histT[b][0..255] -> boffs
// ============================================================
__global__ __launch_bounds__(256) void scan_block2(
    const int* __restrict__ in, int* __restrict__ outlocal, int* __restrict__ bsums)
{
    __shared__ int s[256];
    int i = blockIdx.x * 256 + threadIdx.x;
    int x = in[i];
    s[threadIdx.x] = x;
    __syncthreads();
    #pragma unroll
    for (int o = 1; o < 256; o <<= 1) {
        int t = (threadIdx.x >= o) ? s[threadIdx.x - o] : 0;
        __syncthreads();
        s[threadIdx.x] += t;
        __syncthreads();
    }
    outlocal[i] = s[threadIdx.x] - x;
    if (threadIdx.x == 255) bsums[blockIdx.x] = s[255];
}

// ============================================================
// scatter2: edges -> bucket-contiguous tmp; bucket bases computed in-block
// ============================================================
__global__ __launch_bounds__(256) void scatter2(
    const int* __restrict__ src, const int* __restrict__ dst,
    const int* __restrict__ boffs, const int* __restrict__ bsums,
    unsigned* __restrict__ tmp)
{
    __shared__ int cur[NBUK];
    __shared__ int bsc[NBUK];
    __shared__ int s[256];
    int bid = blockIdx.x, tid = threadIdx.x;
    if (tid < NBUK) cur[tid] = 0;
    int x = (tid < NBUK) ? bsums[tid] : 0;
    s[tid] = x;
    __syncthreads();
    #pragma unroll
    for (int o = 1; o < 256; o <<= 1) {
        int t = (tid >= o) ? s[tid - o] : 0;
        __syncthreads();
        s[tid] += t;
        __syncthreads();
    }
    if (tid < NBUK) bsc[tid] = s[tid] - x;
    __syncthreads();

    for (int i = tid; i < EPB; i += 256) {
        int e = bid * EPB + i;
        int d = dst[e];
        int sv = src[e];
        int j = d >> 9;
        int r = atomicAdd(&cur[j], 1);
        int pos = boffs[j * NSB + bid] + bsc[j] + r;
        tmp[pos] = ((unsigned)(d & 511) << 17) | (unsigned)sv;
    }
}

// ============================================================
// bucket_sort: one block per bucket (512 nodes); counting sort by dst low
//   9 bits in LDS; bucket base computed in-block; emits sorted_src + offs
// ============================================================
__global__ __launch_bounds__(256) void bucket_sort(
    const unsigned* __restrict__ tmp, const int* __restrict__ bsums,
    int* __restrict__ sorted_src, int* __restrict__ offs)
{
    int bid = blockIdx.x, tid = threadIdx.x;

    __shared__ int h[512];
    __shared__ int o_[512];
    __shared__ int s_[256];
    __shared__ int baseSh;

    int x = (tid < NBUK) ? bsums[tid] : 0;
    s_[tid] = x;
    __syncthreads();
    #pragma unroll
    for (int o = 1; o < 256; o <<= 1) {
        int t = (tid >= o) ? s_[tid - o] : 0;
        __syncthreads();
        s_[tid] += t;
        __syncthreads();
    }
    if (tid == bid) baseSh = s_[tid] - x;
    h[tid] = 0; h[tid + 256] = 0;
    __syncthreads();
    int base = baseSh;
    int cnt  = bsums[bid];

    for (int i = tid; i < cnt; i += 256)
        atomicAdd(&h[tmp[base + i] >> 17], 1);
    __syncthreads();

    int a0 = h[2 * tid], a1 = h[2 * tid + 1];
    s_[tid] = a0 + a1;
    __syncthreads();
    #pragma unroll
    for (int o = 1; o < 256; o <<= 1) {
        int t = (tid >= o) ? s_[tid - o] : 0;
        __syncthreads();
        s_[tid] += t;
        __syncthreads();
    }
    int eb = s_[tid] - a0 - a1;
    o_[2 * tid] = eb;
    o_[2 * tid + 1] = eb + a0;
    __syncthreads();

    for (int t = tid; t < 512; t += 256) {
        int n = bid * 512 + t;
        if (n < N_NODES) offs[n] = base + o_[t];
    }
    __syncthreads();

    for (int i = tid; i < cnt; i += 256) {
        unsigned rec = tmp[base + i];
        int r = atomicAdd(&o_[rec >> 17], 1);
        sorted_src[base + r] = (int)((rec & 0x1FFFFu) << 7);  // src*128
    }
}

// ============================================================
// MFMA GEMM v3: LDS-staged A + epilogue; B loads coalesced via
//   fragment-ordered Wtb (256B contiguous per 16-lane group)
// ============================================================
__global__ __launch_bounds__(256) void gemm_mfma(
    const float* __restrict__ feat, const unsigned short* __restrict__ Wtb,
    const float* __restrict__ bq, const float* __restrict__ bk,
    const float* __restrict__ bv, const float* __restrict__ bs,
    unsigned char* __restrict__ q8, __half* __restrict__ vh,
    __half* __restrict__ ks_)
{
    __shared__ __align__(16) unsigned short Atile[32][136];   // 272 B rows
    __shared__ __align__(16) unsigned char  Oq8[32][144];     // 128 used
    __shared__ __align__(16) unsigned char  Ovh[32][272];     // 256 used
    __shared__ __align__(16) unsigned char  Oks[32][528];     // 512 used

    const int tid = threadIdx.x;
    const int r0  = blockIdx.x * 32;     // 3125 * 32 = 100000 exact

    {
        int row = tid >> 3;
        int cg  = (tid & 7) * 16;
        const float4* fp = (const float4*)(feat + (size_t)(r0 + row) * 128 + cg);
        float4 f0 = fp[0], f1 = fp[1], f2 = fp[2], f3 = fp[3];
        unsigned short* ap = &Atile[row][cg];
        ap[0]  = (unsigned short)f2bf_s(f0.x); ap[1]  = (unsigned short)f2bf_s(f0.y);
        ap[2]  = (unsigned short)f2bf_s(f0.z); ap[3]  = (unsigned short)f2bf_s(f0.w);
        ap[4]  = (unsigned short)f2bf_s(f1.x); ap[5]  = (unsigned short)f2bf_s(f1.y);
        ap[6]  = (unsigned short)f2bf_s(f1.z); ap[7]  = (unsigned short)f2bf_s(f1.w);
        ap[8]  = (unsigned short)f2bf_s(f2.x); ap[9]  = (unsigned short)f2bf_s(f2.y);
        ap[10] = (unsigned short)f2bf_s(f2.z); ap[11] = (unsigned short)f2bf_s(f2.w);
        ap[12] = (unsigned short)f2bf_s(f3.x); ap[13] = (unsigned short)f2bf_s(f3.y);
        ap[14] = (unsigned short)f2bf_s(f3.z); ap[15] = (unsigned short)f2bf_s(f3.w);
    }
    __syncthreads();

    const int mat = tid >> 6;
    const int l   = tid & 63;
    const int lr  = l & 15;
    const int lg  = l >> 4;
    const float* bias = (mat == 0) ? bq : (mat == 1) ? bk : (mat == 2) ? bv : bs;

    f32x4 acc[2][8];
    #pragma unroll
    for (int i = 0; i < 2; i++)
        #pragma unroll
        for (int j = 0; j < 8; j++) acc[i][j] = (f32x4){0.f, 0.f, 0.f, 0.f};

    // fragment-ordered Wtb base for this wave: mat*16384 + lg*1024 + lr*8
    const unsigned short* wb = Wtb + (size_t)mat * 16384 + lg * 1024 + lr * 8;

    #pragma unroll
    for (int kks = 0; kks < 4; kks++) {
        const int k0 = kks * 32 + lg * 8;
        bf16x8 a[2], b[8];
        #pragma unroll
        for (int rf = 0; rf < 2; rf++)
            a[rf] = *(const bf16x8*)&Atile[rf * 16 + lr][k0];
        #pragma unroll
        for (int cf = 0; cf < 8; cf++)
            b[cf] = *(const bf16x8*)(wb + kks * 4096 + cf * 128);
        #pragma unroll
        for (int rf = 0; rf < 2; rf++)
            #pragma unroll
            for (int cf = 0; cf < 8; cf++)
                acc[rf][cf] = __builtin_amdgcn_mfma_f32_16x16x32_bf16(
                    b[cf], a[rf], acc[rf][cf], 0, 0, 0);
    }

    #pragma unroll
    for (int rf = 0; rf < 2; rf++) {
        int rl = rf * 16 + lr;
        #pragma unroll
        for (int cf = 0; cf < 8; cf++) {
            int colb = cf * 16 + lg * 4;
            float4 b4 = *(const float4*)(bias + colb);
            float a0 = acc[rf][cf][0] + b4.x, a1 = acc[rf][cf][1] + b4.y;
            float a2 = acc[rf][cf][2] + b4.z, a3 = acc[rf][cf][3] + b4.w;
            if (mat == 0) {
                unsigned u = (unsigned)__builtin_amdgcn_cvt_pk_fp8_f32(a0, a1, 0, false);
                u = (unsigned)__builtin_amdgcn_cvt_pk_fp8_f32(a2, a3, (int)u, true);
                *(unsigned*)&Oq8[rl][colb] = u;
            } else if (mat == 2) {
                uint2 pk; pk.x = pack2h(a0, a1); pk.y = pack2h(a2, a3);
                *(uint2*)&Ovh[rl][colb * 2] = pk;
            } else {
                uint2 pk; pk.x = pack2h(a0, a1); pk.y = pack2h(a2, a3);
                *(uint2*)&Oks[rl][((mat == 3) ? 256 : 0) + colb * 2] = pk;
            }
        }
    }
    __syncthreads();

    {
        int row = tid >> 3;
        int c16 = (tid & 7) * 16;
        *(uint4*)(q8 + (size_t)(r0 + row) * 128 + c16) = *(const uint4*)&Oq8[row][c16];
        {
            char* gp = (char*)vh + (size_t)(r0 + row) * 256 + (tid & 7) * 32;
            const char* lp = (const char*)&Ovh[row][0] + (tid & 7) * 32;
            ((uint4*)gp)[0] = ((const uint4*)lp)[0];
            ((uint4*)gp)[1] = ((const uint4*)lp)[1];
        }
        {
            char* gp = (char*)ks_ + (size_t)(r0 + row) * 512 + (tid & 7) * 64;
            const char* lp = (const char*)&Oks[row][0] + (tid & 7) * 64;
            ((uint4*)gp)[0] = ((const uint4*)lp)[0];
            ((uint4*)gp)[1] = ((const uint4*)lp)[1];
            ((uint4*)gp)[2] = ((const uint4*)lp)[2];
            ((uint4*)gp)[3] = ((const uint4*)lp)[3];
        }
    }
}

// ============================================================
// fused dst-centric aggregation + gate + LN + PReLU
// ============================================================
__global__ __launch_bounds__(256) void node_fused(
    const unsigned char* __restrict__ q8, const __half* __restrict__ vh,
    const __half* __restrict__ ks_,
    const int* __restrict__ offs, const int* __restrict__ sorted_src,
    const float* __restrict__ wg, const float* __restrict__ bg,
    const float* __restrict__ gamma, const float* __restrict__ beta,
    const float* __restrict__ pa, float* __restrict__ out)
{
    int wid = threadIdx.x >> 6;
    int l   = threadIdx.x & 63;
    int qtr = l >> 4;
    int c   = l & 15;
    int n = blockIdx.x * 4 + wid;
    if (n >= N_NODES) return;

    int start = offs[n];
    int end   = (n + 1 < N_NODES) ? offs[n + 1] : N_EDGES;

    const uint4* krow = (const uint4*)ks_;
    uint4 kp  = krow[(size_t)n * 32 + c];
    uint4 sp4 = krow[(size_t)n * 32 + 16 + c];

    f32x2 kp0, kp1, kp2, kp3;
    {
        __half2 h;
        h = bc2(kp.x); kp0 = (f32x2){__low2float(h), __high2float(h)};
        h = bc2(kp.y); kp1 = (f32x2){__low2float(h), __high2float(h)};
        h = bc2(kp.z); kp2 = (f32x2){__low2float(h), __high2float(h)};
        h = bc2(kp.w); kp3 = (f32x2){__low2float(h), __high2float(h)};
    }

    float den = 0.f;
    __half2 ag0 = bc2(0u), ag1 = bc2(0u), ag2 = bc2(0u), ag3 = bc2(0u);
    const float C = 0.25503483f;   // (1/sqrt(32)) * log2(e)

    const char* qb = (const char*)q8 + c * 8;     // + src*128
    const char* vb = (const char*)vh + c * 16;    // + src*256

    int base = start;
    int sA = sorted_src[min(base + qtr, end - 1)];
    uint2 qA = *(const uint2*)(qb + sA);
    uint4 vA = *(const uint4*)(vb + 2 * (size_t)sA);
    bool hasB = (base + 4) < end;
    uint2 qB; uint4 vB;
    if (hasB) {
        int sB = sorted_src[min(base + 4 + qtr, end - 1)];
        qB = *(const uint2*)(qb + sB);
        vB = *(const uint4*)(vb + 2 * (size_t)sB);
    }
    int sC = ((base + 8) < end) ? sorted_src[min(base + 8 + qtr, end - 1)] : 0;

    for (;;) {
        bool hasC = (base + 8) < end;
        uint2 qC; uint4 vC;
        if (hasC) {
            qC = *(const uint2*)(qb + sC);
            vC = *(const uint4*)(vb + 2 * (size_t)sC);
        }
        int sD = ((base + 12) < end) ? sorted_src[min(base + 12 + qtr, end - 1)] : 0;

        f32x2 q01 = __builtin_amdgcn_cvt_pk_f32_fp8((int)qA.x, false);
        f32x2 q23 = __builtin_amdgcn_cvt_pk_f32_fp8((int)qA.x, true);
        f32x2 q45 = __builtin_amdgcn_cvt_pk_f32_fp8((int)qA.y, false);
        f32x2 q67 = __builtin_amdgcn_cvt_pk_f32_fp8((int)qA.y, true);
        f32x2 d2 = q01 * kp0 + q23 * kp1 + q45 * kp2 + q67 * kp3;
        float d = d2[0] + d2[1];
        d += __shfl_xor(d, 1);
        d += __shfl_xor(d, 2);
        float e = (base + qtr < end) ? __builtin_amdgcn_exp2f(d * C) : 0.f;
        den += e;
        __half2 e2 = __float2half2_rn(e);
        ag0 = __hfma2(e2, bc2(vA.x), ag0);
        ag1 = __hfma2(e2, bc2(vA.y), ag1);
        ag2 = __hfma2(e2, bc2(vA.z), ag2);
        ag3 = __hfma2(e2, bc2(vA.w), ag3);

        if (!hasB) break;
        base += 4;
        qA = qB; vA = vB; qB = qC; vB = vC; sC = sD; hasB = hasC;
    }

    den += __shfl_xor(den, 16);
    den += __shfl_xor(den, 32);
    ag0 = __hadd2(ag0, bc2(__shfl_xor(bcu(ag0), 16)));
    ag1 = __hadd2(ag1, bc2(__shfl_xor(bcu(ag1), 16)));
    ag2 = __hadd2(ag2, bc2(__shfl_xor(bcu(ag2), 16)));
    ag3 = __hadd2(ag3, bc2(__shfl_xor(bcu(ag3), 16)));
    ag0 = __hadd2(ag0, bc2(__shfl_xor(bcu(ag0), 32)));
    ag1 = __hadd2(ag1, bc2(__shfl_xor(bcu(ag1), 32)));
    ag2 = __hadd2(ag2, bc2(__shfl_xor(bcu(ag2), 32)));
    ag3 = __hadd2(ag3, bc2(__shfl_xor(bcu(ag3), 32)));

    float rd = 1.f / den;
    float r[8];
    r[0] = __low2float(ag0) * rd; r[1] = __high2float(ag0) * rd;
    r[2] = __low2float(ag1) * rd; r[3] = __high2float(ag1) * rd;
    r[4] = __low2float(ag2) * rd; r[5] = __high2float(ag2) * rd;
    r[6] = __low2float(ag3) * rd; r[7] = __high2float(ag3) * rd;

    float s[8];
    s[0] = __low2float(bc2(sp4.x)); s[1] = __high2float(bc2(sp4.x));
    s[2] = __low2float(bc2(sp4.y)); s[3] = __high2float(bc2(sp4.y));
    s[4] = __low2float(bc2(sp4.z)); s[5] = __high2float(bc2(sp4.z));
    s[6] = __low2float(bc2(sp4.w)); s[7] = __high2float(bc2(sp4.w));

    const float4* wgf = (const float4*)wg;
    float4 w0a = wgf[2 * c],      w0b = wgf[2 * c + 1];
    float4 w1a = wgf[32 + 2 * c], w1b = wgf[32 + 2 * c + 1];
    float4 w2a = wgf[64 + 2 * c], w2b = wgf[64 + 2 * c + 1];
    float w0[8] = {w0a.x, w0a.y, w0a.z, w0a.w, w0b.x, w0b.y, w0b.z, w0b.w};
    float w1[8] = {w1a.x, w1a.y, w1a.z, w1a.w, w1b.x, w1b.y, w1b.z, w1b.w};
    float w2[8] = {w2a.x, w2a.y, w2a.z, w2a.w, w2b.x, w2b.y, w2b.z, w2b.w};

    float gs = 0.f;
    #pragma unroll
    for (int j = 0; j < 8; j++)
        gs += s[j] * w0[j] + r[j] * w1[j] + (s[j] - r[j]) * w2[j];
    gs += __shfl_xor(gs, 1);
    gs += __shfl_xor(gs, 2);
    gs += __shfl_xor(gs, 4);
    gs += __shfl_xor(gs, 8);
    float g = 1.f / (1.f + __builtin_amdgcn_exp2f(-(gs + bg[0]) * 1.4426950408889634f));

    #pragma unroll
    for (int j = 0; j < 8; j++) r[j] = g * s[j] + (1.f - g) * r[j];

    float mu = 0.f;
    #pragma unroll
    for (int j = 0; j < 8; j++) mu += r[j];
    mu += __shfl_xor(mu, 1);
    mu += __shfl_xor(mu, 2);
    mu += __shfl_xor(mu, 4);
    mu += __shfl_xor(mu, 8);
    mu *= (1.f / 128.f);

    float var = 0.f;
    #pragma unroll
    for (int j = 0; j < 8; j++) { float e0 = r[j] - mu; var += e0 * e0; }
    var += __shfl_xor(var, 1);
    var += __shfl_xor(var, 2);
    var += __shfl_xor(var, 4);
    var += __shfl_xor(var, 8);
    var *= (1.f / 128.f);
    float inv = rsqrtf(var + 1e-5f);

    if (qtr == 0) {
        float4 ga = ((const float4*)gamma)[2 * c], gb = ((const float4*)gamma)[2 * c + 1];
        float4 ba = ((const float4*)beta)[2 * c],  bb = ((const float4*)beta)[2 * c + 1];
        float gm[8] = {ga.x, ga.y, ga.z, ga.w, gb.x, gb.y, gb.z, gb.w};
        float bt[8] = {ba.x, ba.y, ba.z, ba.w, bb.x, bb.y, bb.z, bb.w};
        float al = pa[0];
        float y[8];
        #pragma unroll
        for (int j = 0; j < 8; j++) {
            float t = (r[j] - mu) * inv * gm[j] + bt[j];
            y[j] = (t > 0.f) ? t : al * t;
        }
        float4* op = (float4*)(out + (size_t)n * 128 + c * 8);
        op[0] = (float4){y[0], y[1], y[2], y[3]};
        op[1] = (float4){y[4], y[5], y[6], y[7]};
    }
}

// ============================================================
extern "C" void kernel_launch(void* const* d_in, const int* in_sizes, int n_in,
                              void* d_out, int out_size, void* d_ws, size_t ws_size,
                              hipStream_t stream) {
    const float* feat  = (const float*)d_in[0];
    const int*   src   = (const int*)d_in[1];
    const int*   dst   = (const int*)d_in[2];
    const float* Wq    = (const float*)d_in[3];
    const float* bq    = (const float*)d_in[4];
    const float* Wk    = (const float*)d_in[5];
    const float* bk    = (const float*)d_in[6];
    const float* Wv    = (const float*)d_in[7];
    const float* bv    = (const float*)d_in[8];
    const float* Wsk   = (const float*)d_in[9];
    const float* bsk   = (const float*)d_in[10];
    const float* Wg    = (const float*)d_in[11];
    const float* bg    = (const float*)d_in[12];
    const float* gamma = (const float*)d_in[13];
    const float* beta  = (const float*)d_in[14];
    const float* pa    = (const float*)d_in[15];
    float* out = (float*)d_out;

    char* p = (char*)d_ws;
    unsigned char* q8  = (unsigned char*)p;  p += (size_t)N_NODES * 128;       // 12.8 MB
    __half*        vh  = (__half*)p;         p += (size_t)N_NODES * 128 * 2;   // 25.6 MB
    __half*        ks_ = (__half*)p;         p += (size_t)N_NODES * 256 * 2;   // 51.2 MB
    unsigned short* Wtb = (unsigned short*)p;  p += (size_t)4 * 128 * 128 * 2;
    int*      sorted_src = (int*)p;      p += (size_t)N_EDGES * 4;
    unsigned* tmp        = (unsigned*)p; p += (size_t)N_EDGES * 4;
    int*      histT      = (int*)p;      p += (size_t)NBUK * NSB * 4;
    int*      boffs      = (int*)p;      p += (size_t)NBUK * NSB * 4;
    int*      offs       = (int*)p;      p += (size_t)N_NODES * 4;
    int*      bsums      = (int*)p;      p += 4096;

    hist2_wt<<<NSB + 256, 256, 0, stream>>>(dst, Wq, Wk, Wv, Wsk, histT, Wtb);
    scan_block2<<<NBUK, 256, 0, stream>>>(histT, boffs, bsums);
    scatter2<<<NSB, 256, 0, stream>>>(src, dst, boffs, bsums, tmp);
    bucket_sort<<<NBUK, 256, 0, stream>>>(tmp, bsums, sorted_src, offs);
    gemm_mfma<<<3125, 256, 0, stream>>>(feat, Wtb, bq, bk, bv, bsk, q8, vh, ks_);
    node_fused<<<(N_NODES + 3) / 4, 256, 0, stream>>>(q8, vh, ks_, offs, sorted_src,
                                                      Wg, bg, gamma, beta, pa, out);
}

// Round 18
// 199.984 us; speedup vs baseline: 1.6088x; 1.0289x over previous
//
#include <hip/hip_runtime.h>
#include <hip/hip_bf16.h>
#include <hip/hip_fp16.h>
#include <math.h>

#define N_NODES 100000
#define N_EDGES 1600000
#define NBUK 196          // buckets = dst>>9 ; 99999>>9 = 195
#define NSB  256          // hist/scatter blocks
#define EPB  6250         // edges per block (256*6250 = 1.6M exact)
#define GEMM_BLOCKS 3125  // 3125*32 = 100000 rows
// IN=128, HD=128, H=4, D=32

typedef __attribute__((ext_vector_type(8))) short bf16x8;
typedef __attribute__((ext_vector_type(4))) float f32x4;
typedef __attribute__((ext_vector_type(2))) float f32x2;

__device__ __forceinline__ short f2bf_s(float x) {
    __hip_bfloat16 b = __float2bfloat16(x);
    return *reinterpret_cast<short*>(&b);
}
__device__ __forceinline__ __half2 bc2(unsigned u) {
    return *reinterpret_cast<__half2*>(&u);
}
__device__ __forceinline__ unsigned bcu(__half2 h) {
    return *reinterpret_cast<unsigned*>(&h);
}
__device__ __forceinline__ unsigned pack2h(float a, float b) {
    __half ha = __float2half(a), hb = __float2half(b);
    return (unsigned)*reinterpret_cast<unsigned short*>(&ha)
         | ((unsigned)*reinterpret_cast<unsigned short*>(&hb) << 16);
}

// ============================================================
// hist2_wt: blocks 0..255 = per-block bucket histogram (per-wave LDS copies)
//           blocks 256..511 = W -> bf16 in MFMA-fragment order:
//   Wtb[mat][kks][lg][cf][lr][j8] = W[kks*32+lg*8+j8][cf*16+lr]
// ============================================================
__global__ __launch_bounds__(256) void hist2_wt(
    const int* __restrict__ dst,
    const float* __restrict__ Wq, const float* __restrict__ Wk,
    const float* __restrict__ Wv, const float* __restrict__ Ws,
    int* __restrict__ histT, unsigned short* __restrict__ Wtb)
{
    int bid = blockIdx.x, tid = threadIdx.x;
    if (bid < NSB) {
        __shared__ int h[4 * NBUK];
        for (int t = tid; t < 4 * NBUK; t += 256) h[t] = 0;
        __syncthreads();
        int w = tid >> 6;
        for (int i = tid; i < EPB; i += 256)
            atomicAdd(&h[w * NBUK + (dst[bid * EPB + i] >> 9)], 1);
        __syncthreads();
        if (tid < NBUK)
            histT[tid * NSB + bid] = h[tid] + h[NBUK + tid]
                                   + h[2 * NBUK + tid] + h[3 * NBUK + tid];
    } else {
        int j = (bid - NSB) * 256 + tid;   // [0, 65536)
        int j8  = j & 7;
        int lr  = (j >> 3) & 15;
        int cf  = (j >> 7) & 7;
        int lg  = (j >> 10) & 3;
        int kks = (j >> 12) & 3;
        int m   = j >> 14;
        int k   = kks * 32 + lg * 8 + j8;
        int col = cf * 16 + lr;
        const float* W = (m == 0) ? Wq : (m == 1) ? Wk : (m == 2) ? Wv : Ws;
        Wtb[j] = (unsigned short)f2bf_s(W[(size_t)k * 128 + col]);
    }
}

// ============================================================
// scan_block2: grid = NBUK; block b scans histT[b][0..255] -> boffs
// ============================================================
__global__ __launch_bounds__(256) void scan_block2(
    const int* __restrict__ in, int* __restrict__ outlocal, int* __restrict__ bsums)
{
    __shared__ int s[256];
    int i = blockIdx.x * 256 + threadIdx.x;
    int x = in[i];
    s[threadIdx.x] = x;
    __syncthreads();
    #pragma unroll
    for (int o = 1; o < 256; o <<= 1) {
        int t = (threadIdx.x >= o) ? s[threadIdx.x - o] : 0;
        __syncthreads();
        s[threadIdx.x] += t;
        __syncthreads();
    }
    outlocal[i] = s[threadIdx.x] - x;
    if (threadIdx.x == 255) bsums[blockIdx.x] = s[255];
}

// ============================================================
// scatter2: edges -> bucket-contiguous tmp; bucket bases computed in-block
// ============================================================
__global__ __launch_bounds__(256) void scatter2(
    const int* __restrict__ src, const int* __restrict__ dst,
    const int* __restrict__ boffs, const int* __restrict__ bsums,
    unsigned* __restrict__ tmp)
{
    __shared__ int cur[NBUK];
    __shared__ int bsc[NBUK];
    __shared__ int s[256];
    int bid = blockIdx.x, tid = threadIdx.x;
    if (tid < NBUK) cur[tid] = 0;
    int x = (tid < NBUK) ? bsums[tid] : 0;
    s[tid] = x;
    __syncthreads();
    #pragma unroll
    for (int o = 1; o < 256; o <<= 1) {
        int t = (tid >= o) ? s[tid - o] : 0;
        __syncthreads();
        s[tid] += t;
        __syncthreads();
    }
    if (tid < NBUK) bsc[tid] = s[tid] - x;
    __syncthreads();

    for (int i = tid; i < EPB; i += 256) {
        int e = bid * EPB + i;
        int d = dst[e];
        int sv = src[e];
        int j = d >> 9;
        int r = atomicAdd(&cur[j], 1);
        int pos = boffs[j * NSB + bid] + bsc[j] + r;
        tmp[pos] = ((unsigned)(d & 511) << 17) | (unsigned)sv;
    }
}

// ============================================================
// gemm_sort: fused dispatch
//   blocks 0..3124: MFMA GEMM (LDS union: Oks aliases Atile -> 30.2KB/block)
//   blocks 3125..3320: bucket_sort (counting sort per bucket -> sorted_src/offs)
// ============================================================
__global__ __launch_bounds__(256) void gemm_sort(
    const float* __restrict__ feat, const unsigned short* __restrict__ Wtb,
    const float* __restrict__ bq, const float* __restrict__ bk,
    const float* __restrict__ bv, const float* __restrict__ bs,
    unsigned char* __restrict__ q8, __half* __restrict__ vh,
    __half* __restrict__ ks_,
    const unsigned* __restrict__ tmp, const int* __restrict__ bsums,
    int* __restrict__ sorted_src, int* __restrict__ offs)
{
    __shared__ __align__(16) union {
        unsigned short Atile[32][136];         // 8704 B  (phase 1)
        unsigned char  Oks[32][528];           // 16896 B (phase 2, k||skip)
        struct { int h[512]; int o_[512]; int s_[256]; int baseSh; } srt;
    } U;
    __shared__ __align__(16) unsigned char Oq8[32][144];   // 4608 B
    __shared__ __align__(16) unsigned char Ovh[32][272];   // 8704 B

    const int tid = threadIdx.x;

    // ---------------- bucket_sort role ----------------
    if (blockIdx.x >= GEMM_BLOCKS) {
        int bid = blockIdx.x - GEMM_BLOCKS;    // bucket id 0..195
        int x = (tid < NBUK) ? bsums[tid] : 0;
        U.srt.s_[tid] = x;
        __syncthreads();
        #pragma unroll
        for (int o = 1; o < 256; o <<= 1) {
            int t = (tid >= o) ? U.srt.s_[tid - o] : 0;
            __syncthreads();
            U.srt.s_[tid] += t;
            __syncthreads();
        }
        if (tid == bid) U.srt.baseSh = U.srt.s_[tid] - x;
        U.srt.h[tid] = 0; U.srt.h[tid + 256] = 0;
        __syncthreads();
        int base = U.srt.baseSh;
        int cnt  = bsums[bid];

        for (int i = tid; i < cnt; i += 256)
            atomicAdd(&U.srt.h[tmp[base + i] >> 17], 1);
        __syncthreads();

        int a0 = U.srt.h[2 * tid], a1 = U.srt.h[2 * tid + 1];
        U.srt.s_[tid] = a0 + a1;
        __syncthreads();
        #pragma unroll
        for (int o = 1; o < 256; o <<= 1) {
            int t = (tid >= o) ? U.srt.s_[tid - o] : 0;
            __syncthreads();
            U.srt.s_[tid] += t;
            __syncthreads();
        }
        int eb = U.srt.s_[tid] - a0 - a1;
        U.srt.o_[2 * tid] = eb;
        U.srt.o_[2 * tid + 1] = eb + a0;
        __syncthreads();

        for (int t = tid; t < 512; t += 256) {
            int n = bid * 512 + t;
            if (n < N_NODES) offs[n] = base + U.srt.o_[t];
        }
        __syncthreads();

        for (int i = tid; i < cnt; i += 256) {
            unsigned rec = tmp[base + i];
            int r = atomicAdd(&U.srt.o_[rec >> 17], 1);
            sorted_src[base + r] = (int)((rec & 0x1FFFFu) << 7);  // src*128
        }
        return;
    }

    // ---------------- GEMM role ----------------
    const int r0 = blockIdx.x * 32;

    {
        int row = tid >> 3;
        int cg  = (tid & 7) * 16;
        const float4* fp = (const float4*)(feat + (size_t)(r0 + row) * 128 + cg);
        float4 f0 = fp[0], f1 = fp[1], f2 = fp[2], f3 = fp[3];
        unsigned short* ap = &U.Atile[row][cg];
        ap[0]  = (unsigned short)f2bf_s(f0.x); ap[1]  = (unsigned short)f2bf_s(f0.y);
        ap[2]  = (unsigned short)f2bf_s(f0.z); ap[3]  = (unsigned short)f2bf_s(f0.w);
        ap[4]  = (unsigned short)f2bf_s(f1.x); ap[5]  = (unsigned short)f2bf_s(f1.y);
        ap[6]  = (unsigned short)f2bf_s(f1.z); ap[7]  = (unsigned short)f2bf_s(f1.w);
        ap[8]  = (unsigned short)f2bf_s(f2.x); ap[9]  = (unsigned short)f2bf_s(f2.y);
        ap[10] = (unsigned short)f2bf_s(f2.z); ap[11] = (unsigned short)f2bf_s(f2.w);
        ap[12] = (unsigned short)f2bf_s(f3.x); ap[13] = (unsigned short)f2bf_s(f3.y);
        ap[14] = (unsigned short)f2bf_s(f3.z); ap[15] = (unsigned short)f2bf_s(f3.w);
    }
    __syncthreads();

    const int mat = tid >> 6;
    const int l   = tid & 63;
    const int lr  = l & 15;
    const int lg  = l >> 4;
    const float* bias = (mat == 0) ? bq : (mat == 1) ? bk : (mat == 2) ? bv : bs;

    f32x4 acc[2][8];
    #pragma unroll
    for (int i = 0; i < 2; i++)
        #pragma unroll
        for (int j = 0; j < 8; j++) acc[i][j] = (f32x4){0.f, 0.f, 0.f, 0.f};

    const unsigned short* wb = Wtb + (size_t)mat * 16384 + lg * 1024 + lr * 8;

    #pragma unroll
    for (int kks = 0; kks < 4; kks++) {
        const int k0 = kks * 32 + lg * 8;
        bf16x8 a[2], b[8];
        #pragma unroll
        for (int rf = 0; rf < 2; rf++)
            a[rf] = *(const bf16x8*)&U.Atile[rf * 16 + lr][k0];
        #pragma unroll
        for (int cf = 0; cf < 8; cf++)
            b[cf] = *(const bf16x8*)(wb + kks * 4096 + cf * 128);
        #pragma unroll
        for (int rf = 0; rf < 2; rf++)
            #pragma unroll
            for (int cf = 0; cf < 8; cf++)
                acc[rf][cf] = __builtin_amdgcn_mfma_f32_16x16x32_bf16(
                    b[cf], a[rf], acc[rf][cf], 0, 0, 0);
    }

    __syncthreads();   // all waves done reading Atile; Oks may now alias it

    #pragma unroll
    for (int rf = 0; rf < 2; rf++) {
        int rl = rf * 16 + lr;
        #pragma unroll
        for (int cf = 0; cf < 8; cf++) {
            int colb = cf * 16 + lg * 4;
            float4 b4 = *(const float4*)(bias + colb);
            float a0 = acc[rf][cf][0] + b4.x, a1 = acc[rf][cf][1] + b4.y;
            float a2 = acc[rf][cf][2] + b4.z, a3 = acc[rf][cf][3] + b4.w;
            if (mat == 0) {
                unsigned u = (unsigned)__builtin_amdgcn_cvt_pk_fp8_f32(a0, a1, 0, false);
                u = (unsigned)__builtin_amdgcn_cvt_pk_fp8_f32(a2, a3, (int)u, true);
                *(unsigned*)&Oq8[rl][colb] = u;
            } else if (mat == 2) {
                uint2 pk; pk.x = pack2h(a0, a1); pk.y = pack2h(a2, a3);
                *(uint2*)&Ovh[rl][colb * 2] = pk;
            } else {
                uint2 pk; pk.x = pack2h(a0, a1); pk.y = pack2h(a2, a3);
                *(uint2*)&U.Oks[rl][((mat == 3) ? 256 : 0) + colb * 2] = pk;
            }
        }
    }
    __syncthreads();

    {
        int row = tid >> 3;
        int c16 = (tid & 7) * 16;
        *(uint4*)(q8 + (size_t)(r0 + row) * 128 + c16) = *(const uint4*)&Oq8[row][c16];
        {
            char* gp = (char*)vh + (size_t)(r0 + row) * 256 + (tid & 7) * 32;
            const char* lp = (const char*)&Ovh[row][0] + (tid & 7) * 32;
            ((uint4*)gp)[0] = ((const uint4*)lp)[0];
            ((uint4*)gp)[1] = ((const uint4*)lp)[1];
        }
        {
            char* gp = (char*)ks_ + (size_t)(r0 + row) * 512 + (tid & 7) * 64;
            const char* lp = (const char*)&U.Oks[row][0] + (tid & 7) * 64;
            ((uint4*)gp)[0] = ((const uint4*)lp)[0];
            ((uint4*)gp)[1] = ((const uint4*)lp)[1];
            ((uint4*)gp)[2] = ((const uint4*)lp)[2];
            ((uint4*)gp)[3] = ((const uint4*)lp)[3];
        }
    }
}

// ============================================================
// fused dst-centric aggregation + gate + LN + PReLU
// ============================================================
__global__ __launch_bounds__(256) void node_fused(
    const unsigned char* __restrict__ q8, const __half* __restrict__ vh,
    const __half* __restrict__ ks_,
    const int* __restrict__ offs, const int* __restrict__ sorted_src,
    const float* __restrict__ wg, const float* __restrict__ bg,
    const float* __restrict__ gamma, const float* __restrict__ beta,
    const float* __restrict__ pa, float* __restrict__ out)
{
    int wid = threadIdx.x >> 6;
    int l   = threadIdx.x & 63;
    int qtr = l >> 4;
    int c   = l & 15;
    int n = blockIdx.x * 4 + wid;
    if (n >= N_NODES) return;

    int start = offs[n];
    int end   = (n + 1 < N_NODES) ? offs[n + 1] : N_EDGES;

    const uint4* krow = (const uint4*)ks_;
    uint4 kp  = krow[(size_t)n * 32 + c];
    uint4 sp4 = krow[(size_t)n * 32 + 16 + c];

    f32x2 kp0, kp1, kp2, kp3;
    {
        __half2 h;
        h = bc2(kp.x); kp0 = (f32x2){__low2float(h), __high2float(h)};
        h = bc2(kp.y); kp1 = (f32x2){__low2float(h), __high2float(h)};
        h = bc2(kp.z); kp2 = (f32x2){__low2float(h), __high2float(h)};
        h = bc2(kp.w); kp3 = (f32x2){__low2float(h), __high2float(h)};
    }

    float den = 0.f;
    __half2 ag0 = bc2(0u), ag1 = bc2(0u), ag2 = bc2(0u), ag3 = bc2(0u);
    const float C = 0.25503483f;   // (1/sqrt(32)) * log2(e)

    const char* qb = (const char*)q8 + c * 8;     // + src*128
    const char* vb = (const char*)vh + c * 16;    // + src*256

    int base = start;
    int sA = sorted_src[min(base + qtr, end - 1)];
    uint2 qA = *(const uint2*)(qb + sA);
    uint4 vA = *(const uint4*)(vb + 2 * (size_t)sA);
    bool hasB = (base + 4) < end;
    uint2 qB; uint4 vB;
    if (hasB) {
        int sB = sorted_src[min(base + 4 + qtr, end - 1)];
        qB = *(const uint2*)(qb + sB);
        vB = *(const uint4*)(vb + 2 * (size_t)sB);
    }
    int sC = ((base + 8) < end) ? sorted_src[min(base + 8 + qtr, end - 1)] : 0;

    for (;;) {
        bool hasC = (base + 8) < end;
        uint2 qC; uint4 vC;
        if (hasC) {
            qC = *(const uint2*)(qb + sC);
            vC = *(const uint4*)(vb + 2 * (size_t)sC);
        }
        int sD = ((base + 12) < end) ? sorted_src[min(base + 12 + qtr, end - 1)] : 0;

        f32x2 q01 = __builtin_amdgcn_cvt_pk_f32_fp8((int)qA.x, false);
        f32x2 q23 = __builtin_amdgcn_cvt_pk_f32_fp8((int)qA.x, true);
        f32x2 q45 = __builtin_amdgcn_cvt_pk_f32_fp8((int)qA.y, false);
        f32x2 q67 = __builtin_amdgcn_cvt_pk_f32_fp8((int)qA.y, true);
        f32x2 d2 = q01 * kp0 + q23 * kp1 + q45 * kp2 + q67 * kp3;
        float d = d2[0] + d2[1];
        d += __shfl_xor(d, 1);
        d += __shfl_xor(d, 2);
        float e = (base + qtr < end) ? __builtin_amdgcn_exp2f(d * C) : 0.f;
        den += e;
        __half2 e2 = __float2half2_rn(e);
        ag0 = __hfma2(e2, bc2(vA.x), ag0);
        ag1 = __hfma2(e2, bc2(vA.y), ag1);
        ag2 = __hfma2(e2, bc2(vA.z), ag2);
        ag3 = __hfma2(e2, bc2(vA.w), ag3);

        if (!hasB) break;
        base += 4;
        qA = qB; vA = vB; qB = qC; vB = vC; sC = sD; hasB = hasC;
    }

    den += __shfl_xor(den, 16);
    den += __shfl_xor(den, 32);
    ag0 = __hadd2(ag0, bc2(__shfl_xor(bcu(ag0), 16)));
    ag1 = __hadd2(ag1, bc2(__shfl_xor(bcu(ag1), 16)));
    ag2 = __hadd2(ag2, bc2(__shfl_xor(bcu(ag2), 16)));
    ag3 = __hadd2(ag3, bc2(__shfl_xor(bcu(ag3), 16)));
    ag0 = __hadd2(ag0, bc2(__shfl_xor(bcu(ag0), 32)));
    ag1 = __hadd2(ag1, bc2(__shfl_xor(bcu(ag1), 32)));
    ag2 = __hadd2(ag2, bc2(__shfl_xor(bcu(ag2), 32)));
    ag3 = __hadd2(ag3, bc2(__shfl_xor(bcu(ag3), 32)));

    float rd = 1.f / den;
    float r[8];
    r[0] = __low2float(ag0) * rd; r[1] = __high2float(ag0) * rd;
    r[2] = __low2float(ag1) * rd; r[3] = __high2float(ag1) * rd;
    r[4] = __low2float(ag2) * rd; r[5] = __high2float(ag2) * rd;
    r[6] = __low2float(ag3) * rd; r[7] = __high2float(ag3) * rd;

    float s[8];
    s[0] = __low2float(bc2(sp4.x)); s[1] = __high2float(bc2(sp4.x));
    s[2] = __low2float(bc2(sp4.y)); s[3] = __high2float(bc2(sp4.y));
    s[4] = __low2float(bc2(sp4.z)); s[5] = __high2float(bc2(sp4.z));
    s[6] = __low2float(bc2(sp4.w)); s[7] = __high2float(bc2(sp4.w));

    const float4* wgf = (const float4*)wg;
    float4 w0a = wgf[2 * c],      w0b = wgf[2 * c + 1];
    float4 w1a = wgf[32 + 2 * c], w1b = wgf[32 + 2 * c + 1];
    float4 w2a = wgf[64 + 2 * c], w2b = wgf[64 + 2 * c + 1];
    float w0[8] = {w0a.x, w0a.y, w0a.z, w0a.w, w0b.x, w0b.y, w0b.z, w0b.w};
    float w1[8] = {w1a.x, w1a.y, w1a.z, w1a.w, w1b.x, w1b.y, w1b.z, w1b.w};
    float w2[8] = {w2a.x, w2a.y, w2a.z, w2a.w, w2b.x, w2b.y, w2b.z, w2b.w};

    float gs = 0.f;
    #pragma unroll
    for (int j = 0; j < 8; j++)
        gs += s[j] * w0[j] + r[j] * w1[j] + (s[j] - r[j]) * w2[j];
    gs += __shfl_xor(gs, 1);
    gs += __shfl_xor(gs, 2);
    gs += __shfl_xor(gs, 4);
    gs += __shfl_xor(gs, 8);
    float g = 1.f / (1.f + __builtin_amdgcn_exp2f(-(gs + bg[0]) * 1.4426950408889634f));

    #pragma unroll
    for (int j = 0; j < 8; j++) r[j] = g * s[j] + (1.f - g) * r[j];

    float mu = 0.f;
    #pragma unroll
    for (int j = 0; j < 8; j++) mu += r[j];
    mu += __shfl_xor(mu, 1);
    mu += __shfl_xor(mu, 2);
    mu += __shfl_xor(mu, 4);
    mu += __shfl_xor(mu, 8);
    mu *= (1.f / 128.f);

    float var = 0.f;
    #pragma unroll
    for (int j = 0; j < 8; j++) { float e0 = r[j] - mu; var += e0 * e0; }
    var += __shfl_xor(var, 1);
    var += __shfl_xor(var, 2);
    var += __shfl_xor(var, 4);
    var += __shfl_xor(var, 8);
    var *= (1.f / 128.f);
    float inv = rsqrtf(var + 1e-5f);

    if (qtr == 0) {
        float4 ga = ((const float4*)gamma)[2 * c], gb = ((const float4*)gamma)[2 * c + 1];
        float4 ba = ((const float4*)beta)[2 * c],  bb = ((const float4*)beta)[2 * c + 1];
        float gm[8] = {ga.x, ga.y, ga.z, ga.w, gb.x, gb.y, gb.z, gb.w};
        float bt[8] = {ba.x, ba.y, ba.z, ba.w, bb.x, bb.y, bb.z, bb.w};
        float al = pa[0];
        float y[8];
        #pragma unroll
        for (int j = 0; j < 8; j++) {
            float t = (r[j] - mu) * inv * gm[j] + bt[j];
            y[j] = (t > 0.f) ? t : al * t;
        }
        float4* op = (float4*)(out + (size_t)n * 128 + c * 8);
        op[0] = (float4){y[0], y[1], y[2], y[3]};
        op[1] = (float4){y[4], y[5], y[6], y[7]};
    }
}

// ============================================================
extern "C" void kernel_launch(void* const* d_in, const int* in_sizes, int n_in,
                              void* d_out, int out_size, void* d_ws, size_t ws_size,
                              hipStream_t stream) {
    const float* feat  = (const float*)d_in[0];
    const int*   src   = (const int*)d_in[1];
    const int*   dst   = (const int*)d_in[2];
    const float* Wq    = (const float*)d_in[3];
    const float* bq    = (const float*)d_in[4];
    const float* Wk    = (const float*)d_in[5];
    const float* bk    = (const float*)d_in[6];
    const float* Wv    = (const float*)d_in[7];
    const float* bv    = (const float*)d_in[8];
    const float* Wsk   = (const float*)d_in[9];
    const float* bsk   = (const float*)d_in[10];
    const float* Wg    = (const float*)d_in[11];
    const float* bg    = (const float*)d_in[12];
    const float* gamma = (const float*)d_in[13];
    const float* beta  = (const float*)d_in[14];
    const float* pa    = (const float*)d_in[15];
    float* out = (float*)d_out;

    char* p = (char*)d_ws;
    unsigned char* q8  = (unsigned char*)p;  p += (size_t)N_NODES * 128;       // 12.8 MB
    __half*        vh  = (__half*)p;         p += (size_t)N_NODES * 128 * 2;   // 25.6 MB
    __half*        ks_ = (__half*)p;         p += (size_t)N_NODES * 256 * 2;   // 51.2 MB
    unsigned short* Wtb = (unsigned short*)p;  p += (size_t)4 * 128 * 128 * 2;
    int*      sorted_src = (int*)p;      p += (size_t)N_EDGES * 4;
    unsigned* tmp        = (unsigned*)p; p += (size_t)N_EDGES * 4;
    int*      histT      = (int*)p;      p += (size_t)NBUK * NSB * 4;
    int*      boffs      = (int*)p;      p += (size_t)NBUK * NSB * 4;
    int*      offs       = (int*)p;      p += (size_t)N_NODES * 4;
    int*      bsums      = (int*)p;      p += 4096;

    hist2_wt<<<NSB + 256, 256, 0, stream>>>(dst, Wq, Wk, Wv, Wsk, histT, Wtb);
    scan_block2<<<NBUK, 256, 0, stream>>>(histT, boffs, bsums);
    scatter2<<<NSB, 256, 0, stream>>>(src, dst, boffs, bsums, tmp);
    gemm_sort<<<GEMM_BLOCKS + NBUK, 256, 0, stream>>>(feat, Wtb, bq, bk, bv, bsk,
                                                      q8, vh, ks_,
                                                      tmp, bsums, sorted_src, offs);
    node_fused<<<(N_NODES + 3) / 4, 256, 0, stream>>>(q8, vh, ks_, offs, sorted_src,
                                                      Wg, bg, gamma, beta, pa, out);
}